// Round 1
// baseline (3731.062 us; speedup 1.0000x reference)
//
#include <hip/hip_runtime.h>
#include <hip/hip_bf16.h>

// Problem: 2-relation GraphConv (user<->item) + per-type linear + edge MLP + softmax(2).
// Restructured: fold W2/W3 with Wp into 128x2 matrices so per-edge work is 2 adds + softmax2.
// Pipeline:
//   memset(deg+agg) -> degree atomics -> rsqrt -> edge scatter (fp32 atomics) ->
//   fold mats -> per-node fused GEMV(+relu+fold) for users & items -> per-edge softmax.

#define H 128

__device__ __forceinline__ unsigned short f2bf(float f) {
    unsigned u = __float_as_uint(f);
    unsigned r = (u + 0x7fffu + ((u >> 16) & 1u)) >> 16;   // RNE
    return (unsigned short)r;
}

__global__ void degree_kernel(const int* __restrict__ src, const int* __restrict__ dst,
                              float* __restrict__ du, float* __restrict__ di, int E) {
    int e = blockIdx.x * 256 + threadIdx.x;
    if (e >= E) return;
    unsafeAtomicAdd(&du[src[e]], 1.0f);
    unsafeAtomicAdd(&di[dst[e]], 1.0f);
}

__global__ void invsqrt_kernel(float* __restrict__ du, float* __restrict__ di, int nu, int ni) {
    int i = blockIdx.x * 256 + threadIdx.x;
    if (i < nu) {
        du[i] = rsqrtf(fmaxf(du[i], 1.0f));
    } else if (i < nu + ni) {
        int j = i - nu;
        di[j] = rsqrtf(fmaxf(di[j], 1.0f));
    }
}

// One thread per (edge, 4-float chunk): 32 chunks per edge.
__global__ void scatter_kernel(const int* __restrict__ src, const int* __restrict__ dst,
                               const float* __restrict__ xu, const float* __restrict__ xi,
                               const float* __restrict__ inv_du, const float* __restrict__ inv_di,
                               float* __restrict__ agg_u, float* __restrict__ agg_i, int nwork) {
    int idx = blockIdx.x * 256 + threadIdx.x;
    if (idx >= nwork) return;
    int e = idx >> 5, t = idx & 31;
    int s = src[e], d = dst[e];
    float wu = inv_du[s], wi = inv_di[d];
    float4 a = ((const float4*)xu)[(size_t)s * 32 + t];   // x_user row chunk
    float4 b = ((const float4*)xi)[(size_t)d * 32 + t];   // x_item row chunk
    float* pi = agg_i + (size_t)d * H + t * 4;            // agg_item[dst] += x_user[src]*inv_du[src]
    unsafeAtomicAdd(pi + 0, a.x * wu);
    unsafeAtomicAdd(pi + 1, a.y * wu);
    unsafeAtomicAdd(pi + 2, a.z * wu);
    unsafeAtomicAdd(pi + 3, a.w * wu);
    float* pu = agg_u + (size_t)s * H + t * 4;            // agg_user[src] += x_item[dst]*inv_di[dst]
    unsafeAtomicAdd(pu + 0, b.x * wi);
    unsafeAtomicAdd(pu + 1, b.y * wi);
    unsafeAtomicAdd(pu + 2, b.z * wi);
    unsafeAtomicAdd(pu + 3, b.w * wi);
}

// mats layout: Ax[256] | Ah[256] | Bx[256] | Bh[256] | cu[2] | ci[2]
__global__ void fold_kernel(const float* __restrict__ W2, const float* __restrict__ b2,
                            const float* __restrict__ W3, const float* __restrict__ b3,
                            const float* __restrict__ Wp, const float* __restrict__ bp,
                            float* __restrict__ mats) {
    int tid = threadIdx.x;            // 256 threads, 1 block
    int j = tid >> 1, c = tid & 1;
    float ax = 0.f, ah = 0.f, bx = 0.f, bh = 0.f;
    for (int m = 0; m < H; ++m) {
        float wpu = Wp[m * 2 + c];
        float wpi = Wp[(H + m) * 2 + c];
        ax += W2[j * H + m] * wpu;
        ah += W2[(H + j) * H + m] * wpu;
        bx += W3[j * H + m] * wpi;
        bh += W3[(H + j) * H + m] * wpi;
    }
    mats[      j * 2 + c] = ax;
    mats[256 + j * 2 + c] = ah;
    mats[512 + j * 2 + c] = bx;
    mats[768 + j * 2 + c] = bh;
    if (tid < 2) {
        float s1 = 0.f, s2 = 0.f;
        for (int m = 0; m < H; ++m) {
            s1 += b2[m] * Wp[m * 2 + tid];
            s2 += b3[m] * Wp[(H + m) * 2 + tid];
        }
        mats[1024 + tid] = s1 + bp[tid];   // bp folded into user-side const
        mats[1026 + tid] = s2;
    }
}

// Fused per-node: h = relu((agg*inv) @ W + b); s = x·Mx + h·Mh + c  (2 outputs per node).
// 8 nodes per block iteration, 32 threads per node, 4 output cols per thread.
// W held in LDS as bf16 (32 KB).
__global__ __launch_bounds__(256) void node_kernel(
    const float* __restrict__ x, const float* __restrict__ agg,
    const float* __restrict__ inv, const float* __restrict__ W,
    const float* __restrict__ bv, const float* __restrict__ Mx,
    const float* __restrict__ Mh, const float* __restrict__ cv,
    float* __restrict__ sout, int n) {
    __shared__ __align__(16) unsigned short Ws[H * H];  // bf16, [k][j]
    __shared__ float aRow[8][H];

    // Stage W -> bf16 LDS (coalesced float4 reads)
    const float4* W4 = (const float4*)W;
    for (int i = threadIdx.x; i < (H * H) / 4; i += 256) {
        float4 w = W4[i];
        ushort4 s4;
        s4.x = f2bf(w.x); s4.y = f2bf(w.y); s4.z = f2bf(w.z); s4.w = f2bf(w.w);
        ((ushort4*)Ws)[i] = s4;
    }

    int g = threadIdx.x >> 5;        // node slot 0..7
    int t = threadIdx.x & 31;        // lane within node
    int j0 = t * 4;                  // 4 consecutive output cols

    for (int base = blockIdx.x * 8; base < n; base += gridDim.x * 8) {
        __syncthreads();             // protects aRow (also covers the W staging on iter 0)
        for (int r = 0; r < 4; ++r) {
            int ii = r * 256 + threadIdx.x;       // 0..1023 -> 8 nodes x 128 cols
            int nd = ii >> 7, col = ii & 127;
            int u = base + nd;
            if (u < n) aRow[nd][col] = agg[(size_t)u * H + col] * inv[u];
        }
        __syncthreads();

        int u = base + g;
        float4 acc = {0.f, 0.f, 0.f, 0.f};
        #pragma unroll 4
        for (int k = 0; k < H; ++k) {
            float a = aRow[g][k];
            uint2 w = *(const uint2*)(Ws + k * H + j0);
            acc.x += a * __uint_as_float(w.x << 16);
            acc.y += a * __uint_as_float(w.x & 0xffff0000u);
            acc.z += a * __uint_as_float(w.y << 16);
            acc.w += a * __uint_as_float(w.y & 0xffff0000u);
        }
        if (u < n) {
            float4 bb = *(const float4*)(bv + j0);
            float h0 = fmaxf(acc.x + bb.x, 0.f);
            float h1 = fmaxf(acc.y + bb.y, 0.f);
            float h2 = fmaxf(acc.z + bb.z, 0.f);
            float h3 = fmaxf(acc.w + bb.w, 0.f);
            float4 xv = *(const float4*)(x + (size_t)u * H + j0);
            float4 mh01 = *(const float4*)(Mh + j0 * 2);
            float4 mh23 = *(const float4*)(Mh + j0 * 2 + 4);
            float4 mx01 = *(const float4*)(Mx + j0 * 2);
            float4 mx23 = *(const float4*)(Mx + j0 * 2 + 4);
            float p0 = h0 * mh01.x + h1 * mh01.z + h2 * mh23.x + h3 * mh23.z
                     + xv.x * mx01.x + xv.y * mx01.z + xv.z * mx23.x + xv.w * mx23.z;
            float p1 = h0 * mh01.y + h1 * mh01.w + h2 * mh23.y + h3 * mh23.w
                     + xv.x * mx01.y + xv.y * mx01.w + xv.z * mx23.y + xv.w * mx23.w;
            #pragma unroll
            for (int off = 1; off < 32; off <<= 1) {
                p0 += __shfl_xor(p0, off);
                p1 += __shfl_xor(p1, off);
            }
            if (t == 0) {
                sout[(size_t)u * 2 + 0] = p0 + cv[0];
                sout[(size_t)u * 2 + 1] = p1 + cv[1];
            }
        }
    }
}

__global__ void edge_kernel(const int* __restrict__ src, const int* __restrict__ dst,
                            const float* __restrict__ su, const float* __restrict__ si,
                            float* __restrict__ out, int E) {
    int e = blockIdx.x * 256 + threadIdx.x;
    if (e >= E) return;
    int s = src[e], d = dst[e];
    float2 a = ((const float2*)su)[s];
    float2 b = ((const float2*)si)[d];
    float l0 = a.x + b.x, l1 = a.y + b.y;
    float m = fmaxf(l0, l1);
    float e0 = __expf(l0 - m), e1 = __expf(l1 - m);
    float r = 1.0f / (e0 + e1);
    float2 o; o.x = e0 * r; o.y = e1 * r;
    ((float2*)out)[e] = o;
}

extern "C" void kernel_launch(void* const* d_in, const int* in_sizes, int n_in,
                              void* d_out, int out_size, void* d_ws, size_t ws_size,
                              hipStream_t stream) {
    const float* x_user = (const float*)d_in[0];
    const float* x_item = (const float*)d_in[1];
    const float* W0 = (const float*)d_in[2];
    const float* b0 = (const float*)d_in[3];
    const float* W1 = (const float*)d_in[4];
    const float* b1 = (const float*)d_in[5];
    const float* W2 = (const float*)d_in[6];
    const float* b2 = (const float*)d_in[7];
    const float* W3 = (const float*)d_in[8];
    const float* b3 = (const float*)d_in[9];
    const float* Wp = (const float*)d_in[10];
    const float* bp = (const float*)d_in[11];
    const int* esrc = (const int*)d_in[12];
    const int* edst = (const int*)d_in[13];

    const int NU = in_sizes[0] / H;
    const int NI = in_sizes[1] / H;
    const int E  = in_sizes[12];

    float* ws = (float*)d_ws;
    size_t o = 0;
    float* inv_du = ws + o; o += (size_t)NU;          // 100000 (mult of 32)
    float* inv_di = ws + o; o += (size_t)NI;          // 50000
    float* agg_u  = ws + o; o += (size_t)NU * H;      // 12.8M
    float* agg_i  = ws + o; o += (size_t)NI * H;      // 6.4M
    size_t zero_floats = o;                           // deg + agg need zeroing
    float* su     = ws + o; o += (size_t)NU * 2;
    float* si     = ws + o; o += (size_t)NI * 2;
    float* mats   = ws + o; o += 1056;

    hipMemsetAsync(d_ws, 0, zero_floats * sizeof(float), stream);

    degree_kernel<<<(E + 255) / 256, 256, 0, stream>>>(esrc, edst, inv_du, inv_di, E);
    invsqrt_kernel<<<(NU + NI + 255) / 256, 256, 0, stream>>>(inv_du, inv_di, NU, NI);

    int nwork = E * 32;
    scatter_kernel<<<(nwork + 255) / 256, 256, 0, stream>>>(
        esrc, edst, x_user, x_item, inv_du, inv_di, agg_u, agg_i, nwork);

    fold_kernel<<<1, 256, 0, stream>>>(W2, b2, W3, b3, Wp, bp, mats);

    // users: h_user = relu((agg_u*inv_du)@W1 + b1); su = x_user·Ax + h·Ah + cu
    node_kernel<<<1024, 256, 0, stream>>>(
        x_user, agg_u, inv_du, W1, b1, mats + 0, mats + 256, mats + 1024, su, NU);
    // items: h_item = relu((agg_i*inv_di)@W0 + b0); si = x_item·Bx + h·Bh + ci
    node_kernel<<<1024, 256, 0, stream>>>(
        x_item, agg_i, inv_di, W0, b0, mats + 512, mats + 768, mats + 1026, si, NI);

    edge_kernel<<<(E + 255) / 256, 256, 0, stream>>>(esrc, edst, su, si, (float*)d_out, E);
}

// Round 2
// 645.664 us; speedup vs baseline: 5.7786x; 5.7786x over previous
//
#include <hip/hip_runtime.h>
#include <hip/hip_bf16.h>

// GraphConv x2 + per-type linear + edge MLP + softmax(2).
// R2: replace fp32 scatter-atomics (4 GB write-through, 3.3 ms) with
// counting-sort CSR build + gather fused into the node GEMV.
//
// Pipeline:
//   memset(cnt) -> hist (int atomics) -> invsqrt -> scan x2 (3-phase) ->
//   fill CSR -> fold mats -> node_gather (users) -> node_gather (items) ->
//   edge softmax.

#define H 128

__device__ __forceinline__ unsigned short f2bf(float f) {
    unsigned u = __float_as_uint(f);
    unsigned r = (u + 0x7fffu + ((u >> 16) & 1u)) >> 16;   // RNE
    return (unsigned short)r;
}

__global__ void hist_kernel(const int* __restrict__ src, const int* __restrict__ dst,
                            int* __restrict__ cu, int* __restrict__ ci, int E) {
    int e = blockIdx.x * 256 + threadIdx.x;
    if (e >= E) return;
    atomicAdd(&cu[src[e]], 1);
    atomicAdd(&ci[dst[e]], 1);
}

__global__ void invsqrt_kernel(const int* __restrict__ cu, const int* __restrict__ ci,
                               float* __restrict__ du, float* __restrict__ di, int nu, int ni) {
    int i = blockIdx.x * 256 + threadIdx.x;
    if (i < nu) {
        du[i] = rsqrtf(fmaxf((float)cu[i], 1.0f));
    } else if (i < nu + ni) {
        int j = i - nu;
        di[j] = rsqrtf(fmaxf((float)ci[j], 1.0f));
    }
}

// ---- 3-phase exclusive scan (1024 elems/block, Hillis-Steele in LDS) ----
__global__ void scan_block(const int* __restrict__ in, int* __restrict__ out,
                           int* __restrict__ bsum, int n) {
    __shared__ int tmp[1024];
    int gid = blockIdx.x * 1024 + threadIdx.x;
    int v = (gid < n) ? in[gid] : 0;
    tmp[threadIdx.x] = v;
    __syncthreads();
    for (int off = 1; off < 1024; off <<= 1) {
        int t = (threadIdx.x >= off) ? tmp[threadIdx.x - off] : 0;
        __syncthreads();
        tmp[threadIdx.x] += t;
        __syncthreads();
    }
    if (gid < n) out[gid] = tmp[threadIdx.x] - v;          // exclusive
    if (threadIdx.x == 1023 && bsum) bsum[blockIdx.x] = tmp[1023];
}

__global__ void scan_fin(int* __restrict__ off, int* __restrict__ cur,
                         const int* __restrict__ bsum, int n, int total) {
    int gid = blockIdx.x * 1024 + threadIdx.x;
    if (gid < n) {
        int v = off[gid] + bsum[blockIdx.x];
        off[gid] = v;
        cur[gid] = v;
    }
    if (gid == 0) off[n] = total;
}

__global__ void fill_kernel(const int* __restrict__ src, const int* __restrict__ dst,
                            int* __restrict__ curU, int* __restrict__ curI,
                            int* __restrict__ valU, int* __restrict__ valI, int E) {
    int e = blockIdx.x * 256 + threadIdx.x;
    if (e >= E) return;
    int s = src[e], d = dst[e];
    valU[atomicAdd(&curU[s], 1)] = d;   // user s's neighbor items
    valI[atomicAdd(&curI[d], 1)] = s;   // item d's neighbor users
}

// mats layout: Ax[256] | Ah[256] | Bx[256] | Bh[256] | cu[2] | ci[2]
__global__ void fold_kernel(const float* __restrict__ W2, const float* __restrict__ b2,
                            const float* __restrict__ W3, const float* __restrict__ b3,
                            const float* __restrict__ Wp, const float* __restrict__ bp,
                            float* __restrict__ mats) {
    int tid = threadIdx.x;            // 256 threads, 1 block
    int j = tid >> 1, c = tid & 1;
    float ax = 0.f, ah = 0.f, bx = 0.f, bh = 0.f;
    for (int m = 0; m < H; ++m) {
        float wpu = Wp[m * 2 + c];
        float wpi = Wp[(H + m) * 2 + c];
        ax += W2[j * H + m] * wpu;
        ah += W2[(H + j) * H + m] * wpu;
        bx += W3[j * H + m] * wpi;
        bh += W3[(H + j) * H + m] * wpi;
    }
    mats[      j * 2 + c] = ax;
    mats[256 + j * 2 + c] = ah;
    mats[512 + j * 2 + c] = bx;
    mats[768 + j * 2 + c] = bh;
    if (tid < 2) {
        float s1 = 0.f, s2 = 0.f;
        for (int m = 0; m < H; ++m) {
            s1 += b2[m] * Wp[m * 2 + tid];
            s2 += b3[m] * Wp[(H + m) * 2 + tid];
        }
        mats[1024 + tid] = s1 + bp[tid];   // bp folded into user-side const
        mats[1026 + tid] = s2;
    }
}

// Fused per-node: gather neighbor rows (CSR) -> aRow; h = relu(aRow@W + b);
// s = x·Mx + h·Mh + c. 8 nodes/block, 32 lanes/node (wave-private LDS slot,
// no barriers in the loop). W in LDS as bf16 (32 KB).
__global__ __launch_bounds__(256) void node_gather_kernel(
    const float* __restrict__ x, const int* __restrict__ off, const int* __restrict__ val,
    const float* __restrict__ xo, const float* __restrict__ invo,
    const float* __restrict__ inv, const float* __restrict__ W,
    const float* __restrict__ bv, const float* __restrict__ Mx,
    const float* __restrict__ Mh, const float* __restrict__ cv,
    float* __restrict__ sout, int n) {
    __shared__ __align__(16) unsigned short Ws[H * H];  // bf16, [k][j]
    __shared__ float aRow[8][H];

    const float4* W4 = (const float4*)W;
    for (int i = threadIdx.x; i < (H * H) / 4; i += 256) {
        float4 w = W4[i];
        ushort4 s4;
        s4.x = f2bf(w.x); s4.y = f2bf(w.y); s4.z = f2bf(w.z); s4.w = f2bf(w.w);
        ((ushort4*)Ws)[i] = s4;
    }
    __syncthreads();                 // Ws ready; loop below is barrier-free

    int g = threadIdx.x >> 5;        // node slot 0..7 (wave-private: slots 2w,2w+1)
    int t = threadIdx.x & 31;        // lane within node
    int j0 = t * 4;                  // 4 consecutive output cols

    for (int base = blockIdx.x * 8; base < n; base += gridDim.x * 8) {
        int u = base + g;
        float ax = 0.f, ay = 0.f, az = 0.f, aw = 0.f;
        float bx2 = 0.f, by2 = 0.f, bz2 = 0.f, bw2 = 0.f;
        if (u < n) {
            int k = off[u], end = off[u + 1];
            for (; k + 2 <= end; k += 2) {        // 2-way ILP on gathered loads
                int v0 = val[k], v1 = val[k + 1];
                float w0 = invo[v0], w1 = invo[v1];
                float4 a0 = ((const float4*)xo)[(size_t)v0 * 32 + t];
                float4 a1 = ((const float4*)xo)[(size_t)v1 * 32 + t];
                ax += a0.x * w0; ay += a0.y * w0; az += a0.z * w0; aw += a0.w * w0;
                bx2 += a1.x * w1; by2 += a1.y * w1; bz2 += a1.z * w1; bw2 += a1.w * w1;
            }
            if (k < end) {
                int v0 = val[k];
                float w0 = invo[v0];
                float4 a0 = ((const float4*)xo)[(size_t)v0 * 32 + t];
                ax += a0.x * w0; ay += a0.y * w0; az += a0.z * w0; aw += a0.w * w0;
            }
            float ws = inv[u];
            ax = (ax + bx2) * ws; ay = (ay + by2) * ws;
            az = (az + bz2) * ws; aw = (aw + bw2) * ws;
        }
        float4 st = {ax, ay, az, aw};
        *((float4*)&aRow[g][j0]) = st;           // wave-private slot; HW keeps
                                                 // per-wave LDS ops in order
        float4 acc = {0.f, 0.f, 0.f, 0.f};
        #pragma unroll 4
        for (int k = 0; k < H; ++k) {
            float a = aRow[g][k];                // LDS broadcast
            uint2 w = *(const uint2*)(Ws + k * H + j0);
            acc.x += a * __uint_as_float(w.x << 16);
            acc.y += a * __uint_as_float(w.x & 0xffff0000u);
            acc.z += a * __uint_as_float(w.y << 16);
            acc.w += a * __uint_as_float(w.y & 0xffff0000u);
        }
        if (u < n) {
            float4 bb = *(const float4*)(bv + j0);
            float h0 = fmaxf(acc.x + bb.x, 0.f);
            float h1 = fmaxf(acc.y + bb.y, 0.f);
            float h2 = fmaxf(acc.z + bb.z, 0.f);
            float h3 = fmaxf(acc.w + bb.w, 0.f);
            float4 xv = *(const float4*)(x + (size_t)u * H + j0);
            float4 mh01 = *(const float4*)(Mh + j0 * 2);
            float4 mh23 = *(const float4*)(Mh + j0 * 2 + 4);
            float4 mx01 = *(const float4*)(Mx + j0 * 2);
            float4 mx23 = *(const float4*)(Mx + j0 * 2 + 4);
            float p0 = h0 * mh01.x + h1 * mh01.z + h2 * mh23.x + h3 * mh23.z
                     + xv.x * mx01.x + xv.y * mx01.z + xv.z * mx23.x + xv.w * mx23.z;
            float p1 = h0 * mh01.y + h1 * mh01.w + h2 * mh23.y + h3 * mh23.w
                     + xv.x * mx01.y + xv.y * mx01.w + xv.z * mx23.y + xv.w * mx23.w;
            #pragma unroll
            for (int o = 1; o < 32; o <<= 1) {
                p0 += __shfl_xor(p0, o);
                p1 += __shfl_xor(p1, o);
            }
            if (t == 0) {
                sout[(size_t)u * 2 + 0] = p0 + cv[0];
                sout[(size_t)u * 2 + 1] = p1 + cv[1];
            }
        }
    }
}

__global__ void edge_kernel(const int* __restrict__ src, const int* __restrict__ dst,
                            const float* __restrict__ su, const float* __restrict__ si,
                            float* __restrict__ out, int E) {
    int e = blockIdx.x * 256 + threadIdx.x;
    if (e >= E) return;
    int s = src[e], d = dst[e];
    float2 a = ((const float2*)su)[s];
    float2 b = ((const float2*)si)[d];
    float l0 = a.x + b.x, l1 = a.y + b.y;
    float m = fmaxf(l0, l1);
    float e0 = __expf(l0 - m), e1 = __expf(l1 - m);
    float r = 1.0f / (e0 + e1);
    float2 o; o.x = e0 * r; o.y = e1 * r;
    ((float2*)out)[e] = o;
}

extern "C" void kernel_launch(void* const* d_in, const int* in_sizes, int n_in,
                              void* d_out, int out_size, void* d_ws, size_t ws_size,
                              hipStream_t stream) {
    const float* x_user = (const float*)d_in[0];
    const float* x_item = (const float*)d_in[1];
    const float* W0 = (const float*)d_in[2];
    const float* b0 = (const float*)d_in[3];
    const float* W1 = (const float*)d_in[4];
    const float* b1 = (const float*)d_in[5];
    const float* W2 = (const float*)d_in[6];
    const float* b2 = (const float*)d_in[7];
    const float* W3 = (const float*)d_in[8];
    const float* b3 = (const float*)d_in[9];
    const float* Wp = (const float*)d_in[10];
    const float* bp = (const float*)d_in[11];
    const int* esrc = (const int*)d_in[12];
    const int* edst = (const int*)d_in[13];

    const int NU = in_sizes[0] / H;
    const int NI = in_sizes[1] / H;
    const int E  = in_sizes[12];

    auto rnd = [](size_t x) { return (x + 63) & ~(size_t)63; };
    char* base = (char*)d_ws;
    size_t o = 0;
    auto alloc = [&](size_t elems) { void* p = base + o * 4; o += rnd(elems); return p; };

    float* inv_du = (float*)alloc(NU);
    float* inv_di = (float*)alloc(NI);
    float* su     = (float*)alloc((size_t)NU * 2);
    float* si     = (float*)alloc((size_t)NI * 2);
    float* mats   = (float*)alloc(1056);
    size_t cnt_off = o;                       // cntU/cntI contiguous for one memset
    int* cntU = (int*)alloc(NU);
    int* cntI = (int*)alloc(NI);
    size_t cnt_words = o - cnt_off;
    int* offU = (int*)alloc(NU + 1);
    int* offI = (int*)alloc(NI + 1);
    int* curU = (int*)alloc(NU);
    int* curI = (int*)alloc(NI);
    int* valU = (int*)alloc(E);
    int* valI = (int*)alloc(E);
    int* bsU  = (int*)alloc(1024);
    int* bsI  = (int*)alloc(1024);

    hipMemsetAsync(cntU, 0, cnt_words * 4, stream);

    hist_kernel<<<(E + 255) / 256, 256, 0, stream>>>(esrc, edst, cntU, cntI, E);
    invsqrt_kernel<<<(NU + NI + 255) / 256, 256, 0, stream>>>(cntU, cntI, inv_du, inv_di, NU, NI);

    int nbU = (NU + 1023) / 1024, nbI = (NI + 1023) / 1024;
    scan_block<<<nbU, 1024, 0, stream>>>(cntU, offU, bsU, NU);
    scan_block<<<nbI, 1024, 0, stream>>>(cntI, offI, bsI, NI);
    scan_block<<<1, 1024, 0, stream>>>(bsU, bsU, nullptr, nbU);
    scan_block<<<1, 1024, 0, stream>>>(bsI, bsI, nullptr, nbI);
    scan_fin<<<nbU, 1024, 0, stream>>>(offU, curU, bsU, NU, E);
    scan_fin<<<nbI, 1024, 0, stream>>>(offI, curI, bsI, NI, E);

    fill_kernel<<<(E + 255) / 256, 256, 0, stream>>>(esrc, edst, curU, curI, valU, valI, E);

    fold_kernel<<<1, 256, 0, stream>>>(W2, b2, W3, b3, Wp, bp, mats);

    // users: gather x_item rows; h = relu((agg*inv_du)@W1+b1); su = x_user·Ax + h·Ah + cu
    node_gather_kernel<<<1024, 256, 0, stream>>>(
        x_user, offU, valU, x_item, inv_di, inv_du, W1, b1,
        mats + 0, mats + 256, mats + 1024, su, NU);
    // items: gather x_user rows; h = relu((agg*inv_di)@W0+b0); si = x_item·Bx + h·Bh + ci
    node_gather_kernel<<<1024, 256, 0, stream>>>(
        x_item, offI, valI, x_user, inv_du, inv_di, W0, b0,
        mats + 512, mats + 768, mats + 1026, si, NI);

    edge_kernel<<<(E + 255) / 256, 256, 0, stream>>>(esrc, edst, su, si, (float*)d_out, E);
}

// Round 3
// 409.889 us; speedup vs baseline: 9.1026x; 1.5752x over previous
//
#include <hip/hip_runtime.h>
#include <hip/hip_bf16.h>

// GraphConv x2 + per-type linear + edge MLP + softmax(2).
// R3: (a) bucketed counting-sort CSR build (kills 4B-scatter line amplification
//     and per-edge atomic round-trips); (b) y = (x*inv)@W precomputed densely
//     (GEMV commutes with segment-sum), stored bf16 -> gather is add-only
//     at 256 B/edge.

#define H 128
#define P2CAP 4096

__device__ __forceinline__ unsigned short f2bf(float f) {
    unsigned u = __float_as_uint(f);
    unsigned r = (u + 0x7fffu + ((u >> 16) & 1u)) >> 16;   // RNE
    return (unsigned short)r;
}
__device__ __forceinline__ float bflo(unsigned b) { return __uint_as_float(b << 16); }
__device__ __forceinline__ float bfhi(unsigned b) { return __uint_as_float(b & 0xffff0000u); }

// ---- P0: coarse bucket histogram (bucket = node >> 7) -------------------
__global__ __launch_bounds__(256) void p0_hist(const int* __restrict__ src,
                                               const int* __restrict__ dst,
                                               int* __restrict__ hU, int* __restrict__ hI,
                                               int E, int nbu, int nbi) {
    __shared__ int lh[1024 + 512];
    for (int i = threadIdx.x; i < nbu + nbi; i += 256) lh[i] = 0;
    __syncthreads();
    for (int e = blockIdx.x * 256 + threadIdx.x; e < E; e += gridDim.x * 256) {
        atomicAdd(&lh[src[e] >> 7], 1);
        atomicAdd(&lh[nbu + (dst[e] >> 7)], 1);
    }
    __syncthreads();
    for (int i = threadIdx.x; i < nbu; i += 256) { int c = lh[i]; if (c) atomicAdd(&hU[i], c); }
    for (int i = threadIdx.x; i < nbi; i += 256) { int c = lh[nbu + i]; if (c) atomicAdd(&hI[i], c); }
}

// ---- scan both bucket histograms (1 block, 1024 threads) ----------------
__global__ void p_scan(const int* __restrict__ hU, const int* __restrict__ hI,
                       int* __restrict__ bOffU, int* __restrict__ bOffI,
                       int* __restrict__ curU, int* __restrict__ curI,
                       int nbu, int nbi, int E) {
    __shared__ int tmp[1024];
    int t = threadIdx.x;
    int v = (t < nbu) ? hU[t] : 0;
    tmp[t] = v; __syncthreads();
    for (int off = 1; off < 1024; off <<= 1) {
        int x = (t >= off) ? tmp[t - off] : 0; __syncthreads();
        tmp[t] += x; __syncthreads();
    }
    if (t < nbu) { int e = tmp[t] - v; bOffU[t] = e; curU[t] = e; }
    if (t == 0) bOffU[nbu] = E;
    __syncthreads();
    v = (t < nbi) ? hI[t] : 0;
    tmp[t] = v; __syncthreads();
    for (int off = 1; off < 1024; off <<= 1) {
        int x = (t >= off) ? tmp[t - off] : 0; __syncthreads();
        tmp[t] += x; __syncthreads();
    }
    if (t < nbi) { int e = tmp[t] - v; bOffI[t] = e; curI[t] = e; }
    if (t == 0) bOffI[nbi] = E;
}

// ---- P1: partition edges into buckets (batched cursor atomics) ----------
__global__ __launch_bounds__(256) void p1_partition(
    const int* __restrict__ src, const int* __restrict__ dst,
    int* __restrict__ gCurU, int* __restrict__ gCurI,
    uint2* __restrict__ pairU, uint2* __restrict__ pairI,
    int E, int nbu, int nbi) {
    __shared__ int cntU[1024], baseU[1024], cntI[512], baseI[512];
    int t0 = blockIdx.x * 4096;
    for (int i = threadIdx.x; i < nbu; i += 256) cntU[i] = 0;
    for (int i = threadIdx.x; i < nbi; i += 256) cntI[i] = 0;
    __syncthreads();
    #pragma unroll
    for (int j = 0; j < 16; ++j) {
        int e = t0 + j * 256 + threadIdx.x;
        if (e < E) { atomicAdd(&cntU[src[e] >> 7], 1); atomicAdd(&cntI[dst[e] >> 7], 1); }
    }
    __syncthreads();
    for (int i = threadIdx.x; i < nbu; i += 256) { int c = cntU[i]; baseU[i] = c ? atomicAdd(&gCurU[i], c) : 0; }
    for (int i = threadIdx.x; i < nbi; i += 256) { int c = cntI[i]; baseI[i] = c ? atomicAdd(&gCurI[i], c) : 0; }
    __syncthreads();
    #pragma unroll
    for (int j = 0; j < 16; ++j) {
        int e = t0 + j * 256 + threadIdx.x;
        if (e < E) {
            int s = src[e], d = dst[e];
            int bu = s >> 7, bi = d >> 7;
            int r1 = atomicSub(&cntU[bu], 1) - 1;
            pairU[baseU[bu] + r1] = make_uint2((unsigned)s, (unsigned)d);
            int r2 = atomicSub(&cntI[bi], 1) - 1;
            pairI[baseI[bi] + r2] = make_uint2((unsigned)d, (unsigned)s);
        }
    }
}

// ---- P2: per-bucket node hist + scan + inv + LDS bin + coalesced CSR ----
__global__ __launch_bounds__(256) void p2_build(
    const uint2* __restrict__ pairs, const int* __restrict__ bOff,
    int* __restrict__ offOut, float* __restrict__ invOut, int* __restrict__ valOut,
    int nTotal, int E) {
    __shared__ int cnt[128], pref[128], cur[128];
    __shared__ int out[P2CAP];
    int b = blockIdx.x, t = threadIdx.x;
    int start = bOff[b], end = bOff[b + 1], size = end - start;
    int nodeBase = b << 7;
    if (t < 128) { cnt[t] = 0; cur[t] = 0; }
    __syncthreads();
    for (int i = start + t; i < end; i += 256) atomicAdd(&cnt[pairs[i].x & 127], 1);
    __syncthreads();
    if (t < 128) pref[t] = cnt[t];
    __syncthreads();
    for (int off = 1; off < 128; off <<= 1) {
        int v = (t < 128 && t >= off) ? pref[t - off] : 0; __syncthreads();
        if (t < 128) pref[t] += v; __syncthreads();
    }
    if (t < 128) {                       // pref is inclusive; exclusive = pref - cnt
        int node = nodeBase + t;
        if (node < nTotal) {
            offOut[node] = start + pref[t] - cnt[t];
            invOut[node] = rsqrtf(fmaxf((float)cnt[t], 1.0f));
        }
    }
    if (b == 0 && t == 0) offOut[nTotal] = E;
    __syncthreads();
    if (size <= P2CAP) {
        for (int i = start + t; i < end; i += 256) {
            uint2 p = pairs[i]; int ln = p.x & 127;
            int r = atomicAdd(&cur[ln], 1);
            out[pref[ln] - cnt[ln] + r] = (int)p.y;
        }
        __syncthreads();
        for (int i = t; i < size; i += 256) valOut[start + i] = out[i];
    } else {                             // safety fallback (never for uniform input)
        for (int i = start + t; i < end; i += 256) {
            uint2 p = pairs[i]; int ln = p.x & 127;
            int r = atomicAdd(&cur[ln], 1);
            valOut[start + pref[ln] - cnt[ln] + r] = (int)p.y;
        }
    }
}

// mats layout: Ax[256] | Ah[256] | Bx[256] | Bh[256] | cu[2] | ci[2]
__global__ void fold_kernel(const float* __restrict__ W2, const float* __restrict__ b2,
                            const float* __restrict__ W3, const float* __restrict__ b3,
                            const float* __restrict__ Wp, const float* __restrict__ bp,
                            float* __restrict__ mats) {
    int tid = threadIdx.x;
    int j = tid >> 1, c = tid & 1;
    float ax = 0.f, ah = 0.f, bx = 0.f, bh = 0.f;
    for (int m = 0; m < H; ++m) {
        float wpu = Wp[m * 2 + c];
        float wpi = Wp[(H + m) * 2 + c];
        ax += W2[j * H + m] * wpu;
        ah += W2[(H + j) * H + m] * wpu;
        bx += W3[j * H + m] * wpi;
        bh += W3[(H + j) * H + m] * wpi;
    }
    mats[      j * 2 + c] = ax;
    mats[256 + j * 2 + c] = ah;
    mats[512 + j * 2 + c] = bx;
    mats[768 + j * 2 + c] = bh;
    if (tid < 2) {
        float s1 = 0.f, s2 = 0.f;
        for (int m = 0; m < H; ++m) {
            s1 += b2[m] * Wp[m * 2 + tid];
            s2 += b3[m] * Wp[(H + m) * 2 + tid];
        }
        mats[1024 + tid] = s1 + bp[tid];
        mats[1026 + tid] = s2;
    }
}

// ---- dense y = (x*inv) @ W, bf16 out. 16 nodes/block-iter, 4 nodes/wave. ----
__global__ __launch_bounds__(256) void ygemv_kernel(
    const float* __restrict__ x, const float* __restrict__ inv,
    const float* __restrict__ W, unsigned short* __restrict__ y, int n) {
    __shared__ __align__(16) unsigned short Ws[H * H];  // [k][j] bf16
    __shared__ float aRow[16][H];
    const float4* W4 = (const float4*)W;
    for (int i = threadIdx.x; i < (H * H) / 4; i += 256) {
        float4 w = W4[i];
        ushort4 s4; s4.x = f2bf(w.x); s4.y = f2bf(w.y); s4.z = f2bf(w.z); s4.w = f2bf(w.w);
        ((ushort4*)Ws)[i] = s4;
    }
    int w = threadIdx.x >> 6, lane = threadIdx.x & 63;
    int r = w * 4;
    int nTiles = (n + 15) >> 4;
    for (int tile = blockIdx.x; tile < nTiles; tile += gridDim.x) {
        __syncthreads();                 // aRow safe (covers Ws staging on iter 0)
        int base = tile << 4;
        for (int i = threadIdx.x; i < 512; i += 256) {   // 16 rows x 32 float4
            int nd = i >> 5, c4 = i & 31;
            int gn = base + nd;
            float4 v = (gn < n) ? ((const float4*)x)[(size_t)gn * 32 + c4] : make_float4(0, 0, 0, 0);
            float s = (gn < n) ? inv[gn] : 0.f;
            v.x *= s; v.y *= s; v.z *= s; v.w *= s;
            *(float4*)&aRow[nd][c4 * 4] = v;
        }
        __syncthreads();
        float2 a0 = {0, 0}, a1 = {0, 0}, a2 = {0, 0}, a3 = {0, 0};
        #pragma unroll 4
        for (int k = 0; k < H; ++k) {
            unsigned wb = *(const unsigned*)&Ws[k * H + lane * 2];
            float f0 = bflo(wb), f1 = bfhi(wb);
            float s0 = aRow[r][k], s1 = aRow[r + 1][k];
            float s2 = aRow[r + 2][k], s3 = aRow[r + 3][k];
            a0.x += s0 * f0; a0.y += s0 * f1;
            a1.x += s1 * f0; a1.y += s1 * f1;
            a2.x += s2 * f0; a2.y += s2 * f1;
            a3.x += s3 * f0; a3.y += s3 * f1;
        }
        int gn = base + r;
        float2 av[4] = {a0, a1, a2, a3};
        #pragma unroll
        for (int i = 0; i < 4; ++i) {
            if (gn + i < n) {
                unsigned pk = ((unsigned)f2bf(av[i].y) << 16) | f2bf(av[i].x);
                *(unsigned*)&y[(size_t)(gn + i) * H + lane * 2] = pk;
            }
        }
    }
}

// ---- gx[u] = x[u]·Mx + c (2 outputs), 32 lanes/node ----
__global__ __launch_bounds__(256) void gx_kernel(const float* __restrict__ x,
                                                 const float* __restrict__ Mx,
                                                 const float* __restrict__ cv,
                                                 float2* __restrict__ gx, int n) {
    int g = threadIdx.x >> 5, t = threadIdx.x & 31, j0 = t * 4;
    float4 mx01 = *(const float4*)(Mx + j0 * 2), mx23 = *(const float4*)(Mx + j0 * 2 + 4);
    float c0 = cv[0], c1 = cv[1];
    for (int u = blockIdx.x * 8 + g; u < n; u += gridDim.x * 8) {
        float4 xv = *(const float4*)(x + (size_t)u * H + j0);
        float p0 = xv.x * mx01.x + xv.y * mx01.z + xv.z * mx23.x + xv.w * mx23.z;
        float p1 = xv.x * mx01.y + xv.y * mx01.w + xv.z * mx23.y + xv.w * mx23.w;
        #pragma unroll
        for (int o = 1; o < 32; o <<= 1) { p0 += __shfl_xor(p0, o); p1 += __shfl_xor(p1, o); }
        if (t == 0) gx[u] = make_float2(p0 + c0, p1 + c1);
    }
}

// ---- gather bf16 y rows + relu + fold; no LDS, no barriers ----
__global__ __launch_bounds__(256) void gather_kernel(
    const int* __restrict__ off, const int* __restrict__ val,
    const unsigned short* __restrict__ yo, const float* __restrict__ inv,
    const float* __restrict__ bv, const float* __restrict__ Mh,
    const float2* __restrict__ gx, float2* __restrict__ sout, int n) {
    int g = threadIdx.x >> 5, t = threadIdx.x & 31, j0 = t * 4;
    float4 bb = *(const float4*)(bv + j0);
    float4 mh01 = *(const float4*)(Mh + j0 * 2), mh23 = *(const float4*)(Mh + j0 * 2 + 4);
    for (int u = blockIdx.x * 8 + g; u < n; u += gridDim.x * 8) {
        int k = off[u], end = off[u + 1];
        float x0 = 0, x1 = 0, x2 = 0, x3 = 0, y0 = 0, y1 = 0, y2 = 0, y3 = 0;
        for (; k + 2 <= end; k += 2) {
            int v0 = val[k], v1 = val[k + 1];
            uint2 w0 = *(const uint2*)(yo + (size_t)v0 * H + t * 4);
            uint2 w1 = *(const uint2*)(yo + (size_t)v1 * H + t * 4);
            x0 += bflo(w0.x); x1 += bfhi(w0.x); x2 += bflo(w0.y); x3 += bfhi(w0.y);
            y0 += bflo(w1.x); y1 += bfhi(w1.x); y2 += bflo(w1.y); y3 += bfhi(w1.y);
        }
        if (k < end) {
            int v0 = val[k];
            uint2 w0 = *(const uint2*)(yo + (size_t)v0 * H + t * 4);
            x0 += bflo(w0.x); x1 += bfhi(w0.x); x2 += bflo(w0.y); x3 += bfhi(w0.y);
        }
        float iv = inv[u];
        float h0 = fmaxf((x0 + y0) * iv + bb.x, 0.f);
        float h1 = fmaxf((x1 + y1) * iv + bb.y, 0.f);
        float h2 = fmaxf((x2 + y2) * iv + bb.z, 0.f);
        float h3 = fmaxf((x3 + y3) * iv + bb.w, 0.f);
        float p0 = h0 * mh01.x + h1 * mh01.z + h2 * mh23.x + h3 * mh23.z;
        float p1 = h0 * mh01.y + h1 * mh01.w + h2 * mh23.y + h3 * mh23.w;
        #pragma unroll
        for (int o = 1; o < 32; o <<= 1) { p0 += __shfl_xor(p0, o); p1 += __shfl_xor(p1, o); }
        if (t == 0) {
            float2 gg = gx[u];
            sout[u] = make_float2(p0 + gg.x, p1 + gg.y);
        }
    }
}

__global__ void edge_kernel(const int* __restrict__ src, const int* __restrict__ dst,
                            const float2* __restrict__ su, const float2* __restrict__ si,
                            float* __restrict__ out, int E) {
    int e = blockIdx.x * 256 + threadIdx.x;
    if (e >= E) return;
    float2 a = su[src[e]];
    float2 b = si[dst[e]];
    float l0 = a.x + b.x, l1 = a.y + b.y;
    float m = fmaxf(l0, l1);
    float e0 = __expf(l0 - m), e1 = __expf(l1 - m);
    float r = 1.0f / (e0 + e1);
    float2 o; o.x = e0 * r; o.y = e1 * r;
    ((float2*)out)[e] = o;
}

extern "C" void kernel_launch(void* const* d_in, const int* in_sizes, int n_in,
                              void* d_out, int out_size, void* d_ws, size_t ws_size,
                              hipStream_t stream) {
    const float* x_user = (const float*)d_in[0];
    const float* x_item = (const float*)d_in[1];
    const float* W0 = (const float*)d_in[2];
    const float* b0 = (const float*)d_in[3];
    const float* W1 = (const float*)d_in[4];
    const float* b1 = (const float*)d_in[5];
    const float* W2 = (const float*)d_in[6];
    const float* b2 = (const float*)d_in[7];
    const float* W3 = (const float*)d_in[8];
    const float* b3 = (const float*)d_in[9];
    const float* Wp = (const float*)d_in[10];
    const float* bp = (const float*)d_in[11];
    const int* esrc = (const int*)d_in[12];
    const int* edst = (const int*)d_in[13];

    const int NU = in_sizes[0] / H;
    const int NI = in_sizes[1] / H;
    const int E  = in_sizes[12];
    const int NBU = (NU + 127) >> 7;
    const int NBI = (NI + 127) >> 7;

    auto rnd = [](size_t x) { return (x + 63) & ~(size_t)63; };
    char* base = (char*)d_ws;
    size_t o = 0;
    auto alloc = [&](size_t elems) { void* p = base + o * 4; o += rnd(elems); return p; };

    float* inv_du = (float*)alloc(NU);
    float* inv_di = (float*)alloc(NI);
    float2* su    = (float2*)alloc((size_t)NU * 2);
    float2* si    = (float2*)alloc((size_t)NI * 2);
    float2* gxU   = (float2*)alloc((size_t)NU * 2);
    float2* gxI   = (float2*)alloc((size_t)NI * 2);
    float* mats   = (float*)alloc(1056);
    size_t hist_off = o;
    int* histU = (int*)alloc(1024);
    int* histI = (int*)alloc(512);
    size_t hist_words = o - hist_off;
    int* bOffU = (int*)alloc(NBU + 1);
    int* bOffI = (int*)alloc(NBI + 1);
    int* curU  = (int*)alloc(NBU);
    int* curI  = (int*)alloc(NBI);
    int* offU  = (int*)alloc(NU + 1);
    int* offI  = (int*)alloc(NI + 1);
    int* valU  = (int*)alloc(E);
    int* valI  = (int*)alloc(E);
    uint2* pairU = (uint2*)alloc((size_t)E * 2);
    uint2* pairI = (uint2*)alloc((size_t)E * 2);
    unsigned short* yU = (unsigned short*)alloc((size_t)NU * 64);  // 128 bf16/row
    unsigned short* yI = (unsigned short*)alloc((size_t)NI * 64);

    hipMemsetAsync(histU, 0, hist_words * 4, stream);

    fold_kernel<<<1, 256, 0, stream>>>(W2, b2, W3, b3, Wp, bp, mats);

    p0_hist<<<256, 256, 0, stream>>>(esrc, edst, histU, histI, E, NBU, NBI);
    p_scan<<<1, 1024, 0, stream>>>(histU, histI, bOffU, bOffI, curU, curI, NBU, NBI, E);
    p1_partition<<<(E + 4095) / 4096, 256, 0, stream>>>(
        esrc, edst, curU, curI, pairU, pairI, E, NBU, NBI);
    p2_build<<<NBU, 256, 0, stream>>>(pairU, bOffU, offU, inv_du, valU, NU, E);
    p2_build<<<NBI, 256, 0, stream>>>(pairI, bOffI, offI, inv_di, valI, NI, E);

    // y_user = (x_user*inv_du)@W0 (feeds item agg); y_item = (x_item*inv_di)@W1
    ygemv_kernel<<<1024, 256, 0, stream>>>(x_user, inv_du, W0, yU, NU);
    ygemv_kernel<<<1024, 256, 0, stream>>>(x_item, inv_di, W1, yI, NI);

    gx_kernel<<<1024, 256, 0, stream>>>(x_user, mats + 0, mats + 1024, gxU, NU);
    gx_kernel<<<1024, 256, 0, stream>>>(x_item, mats + 512, mats + 1026, gxI, NI);

    // su = gxU + relu(inv_du*Σ y_item + b1)·Ah ; si = gxI + relu(inv_di*Σ y_user + b0)·Bh
    gather_kernel<<<2048, 256, 0, stream>>>(offU, valU, yI, inv_du, b1, mats + 256, gxU, su, NU);
    gather_kernel<<<2048, 256, 0, stream>>>(offI, valI, yU, inv_di, b0, mats + 768, gxI, si, NI);

    edge_kernel<<<(E + 255) / 256, 256, 0, stream>>>(esrc, edst, su, si, (float*)d_out, E);
}

// Round 4
// 333.019 us; speedup vs baseline: 11.2037x; 1.2308x over previous
//
#include <hip/hip_runtime.h>
#include <hip/hip_bf16.h>

// GraphConv x2 + per-type linear + edge MLP + softmax(2).
// R4: dense y=(inv*x)@W moved to MFMA (16x16x32 bf16) with fragment-swizzled
//     LDS; gx fused into the same kernel; u32-packed sort pairs; uint4 gather
//     with 4-way ILP; merged launches.

#define H 128
#define P2CAP 4096

typedef __attribute__((ext_vector_type(8))) short bf16x8;
typedef __attribute__((ext_vector_type(4))) float f32x4;

__device__ __forceinline__ unsigned short f2bf(float f) {
    unsigned u = __float_as_uint(f);
    unsigned r = (u + 0x7fffu + ((u >> 16) & 1u)) >> 16;   // RNE
    return (unsigned short)r;
}
__device__ __forceinline__ float bflo(unsigned b) { return __uint_as_float(b << 16); }
__device__ __forceinline__ float bfhi(unsigned b) { return __uint_as_float(b & 0xffff0000u); }
__device__ __forceinline__ float bfu(unsigned short b) { return __uint_as_float((unsigned)b << 16); }

// ---- P0: coarse bucket histogram (bucket = node >> 7) -------------------
__global__ __launch_bounds__(256) void p0_hist(const int* __restrict__ src,
                                               const int* __restrict__ dst,
                                               int* __restrict__ hU, int* __restrict__ hI,
                                               int E, int nbu, int nbi) {
    __shared__ int lh[1024 + 512];
    for (int i = threadIdx.x; i < nbu + nbi; i += 256) lh[i] = 0;
    __syncthreads();
    for (int e = blockIdx.x * 256 + threadIdx.x; e < E; e += gridDim.x * 256) {
        atomicAdd(&lh[src[e] >> 7], 1);
        atomicAdd(&lh[nbu + (dst[e] >> 7)], 1);
    }
    __syncthreads();
    for (int i = threadIdx.x; i < nbu; i += 256) { int c = lh[i]; if (c) atomicAdd(&hU[i], c); }
    for (int i = threadIdx.x; i < nbi; i += 256) { int c = lh[nbu + i]; if (c) atomicAdd(&hI[i], c); }
}

// ---- scan both bucket histograms (1 block, 1024 threads) ----------------
__global__ void p_scan(const int* __restrict__ hU, const int* __restrict__ hI,
                       int* __restrict__ bOffU, int* __restrict__ bOffI,
                       int* __restrict__ curU, int* __restrict__ curI,
                       int nbu, int nbi, int E) {
    __shared__ int tmp[1024];
    int t = threadIdx.x;
    int v = (t < nbu) ? hU[t] : 0;
    tmp[t] = v; __syncthreads();
    for (int off = 1; off < 1024; off <<= 1) {
        int x = (t >= off) ? tmp[t - off] : 0; __syncthreads();
        tmp[t] += x; __syncthreads();
    }
    if (t < nbu) { int e = tmp[t] - v; bOffU[t] = e; curU[t] = e; }
    if (t == 0) bOffU[nbu] = E;
    __syncthreads();
    v = (t < nbi) ? hI[t] : 0;
    tmp[t] = v; __syncthreads();
    for (int off = 1; off < 1024; off <<= 1) {
        int x = (t >= off) ? tmp[t - off] : 0; __syncthreads();
        tmp[t] += x; __syncthreads();
    }
    if (t < nbi) { int e = tmp[t] - v; bOffI[t] = e; curI[t] = e; }
    if (t == 0) bOffI[nbi] = E;
}

// ---- P1: partition edges into buckets; pairs packed (node&127)<<24 | other
__global__ __launch_bounds__(256) void p1_partition(
    const int* __restrict__ src, const int* __restrict__ dst,
    int* __restrict__ gCurU, int* __restrict__ gCurI,
    unsigned* __restrict__ pairU, unsigned* __restrict__ pairI,
    int E, int nbu, int nbi) {
    __shared__ int cntU[1024], baseU[1024], cntI[512], baseI[512];
    int t0 = blockIdx.x * 4096;
    for (int i = threadIdx.x; i < nbu; i += 256) cntU[i] = 0;
    for (int i = threadIdx.x; i < nbi; i += 256) cntI[i] = 0;
    __syncthreads();
    #pragma unroll
    for (int j = 0; j < 16; ++j) {
        int e = t0 + j * 256 + threadIdx.x;
        if (e < E) { atomicAdd(&cntU[src[e] >> 7], 1); atomicAdd(&cntI[dst[e] >> 7], 1); }
    }
    __syncthreads();
    for (int i = threadIdx.x; i < nbu; i += 256) { int c = cntU[i]; baseU[i] = c ? atomicAdd(&gCurU[i], c) : 0; }
    for (int i = threadIdx.x; i < nbi; i += 256) { int c = cntI[i]; baseI[i] = c ? atomicAdd(&gCurI[i], c) : 0; }
    __syncthreads();
    #pragma unroll
    for (int j = 0; j < 16; ++j) {
        int e = t0 + j * 256 + threadIdx.x;
        if (e < E) {
            int s = src[e], d = dst[e];
            int bu = s >> 7, bi = d >> 7;
            int r1 = atomicSub(&cntU[bu], 1) - 1;
            pairU[baseU[bu] + r1] = ((unsigned)(s & 127) << 24) | (unsigned)d;
            int r2 = atomicSub(&cntI[bi], 1) - 1;
            pairI[baseI[bi] + r2] = ((unsigned)(d & 127) << 24) | (unsigned)s;
        }
    }
}

// ---- P2: per-bucket node hist + scan + inv + LDS bin + coalesced CSR ----
__global__ __launch_bounds__(256) void p2_build(
    const unsigned* __restrict__ pairs, const int* __restrict__ bOff,
    int* __restrict__ offOut, float* __restrict__ invOut, int* __restrict__ valOut,
    int nTotal, int E) {
    __shared__ int cnt[128], pref[128], cur[128];
    __shared__ int out[P2CAP];
    int b = blockIdx.x, t = threadIdx.x;
    int start = bOff[b], end = bOff[b + 1], size = end - start;
    int nodeBase = b << 7;
    if (t < 128) { cnt[t] = 0; cur[t] = 0; }
    __syncthreads();
    for (int i = start + t; i < end; i += 256) atomicAdd(&cnt[pairs[i] >> 24], 1);
    __syncthreads();
    if (t < 128) pref[t] = cnt[t];
    __syncthreads();
    for (int off = 1; off < 128; off <<= 1) {
        int v = (t < 128 && t >= off) ? pref[t - off] : 0; __syncthreads();
        if (t < 128) pref[t] += v; __syncthreads();
    }
    if (t < 128) {
        int node = nodeBase + t;
        if (node < nTotal) {
            offOut[node] = start + pref[t] - cnt[t];
            invOut[node] = rsqrtf(fmaxf((float)cnt[t], 1.0f));
        }
    }
    if (b == 0 && t == 0) offOut[nTotal] = E;
    __syncthreads();
    if (size <= P2CAP) {
        for (int i = start + t; i < end; i += 256) {
            unsigned p = pairs[i]; int ln = p >> 24;
            int r = atomicAdd(&cur[ln], 1);
            out[pref[ln] - cnt[ln] + r] = (int)(p & 0xFFFFFF);
        }
        __syncthreads();
        for (int i = t; i < size; i += 256) valOut[start + i] = out[i];
    } else {
        for (int i = start + t; i < end; i += 256) {
            unsigned p = pairs[i]; int ln = p >> 24;
            int r = atomicAdd(&cur[ln], 1);
            valOut[start + pref[ln] - cnt[ln] + r] = (int)(p & 0xFFFFFF);
        }
    }
}

// mats layout: Ax[256] | Ah[256] | Bx[256] | Bh[256] | cu[2] | ci[2]
__global__ void fold_kernel(const float* __restrict__ W2, const float* __restrict__ b2,
                            const float* __restrict__ W3, const float* __restrict__ b3,
                            const float* __restrict__ Wp, const float* __restrict__ bp,
                            float* __restrict__ mats) {
    int tid = threadIdx.x;
    int j = tid >> 1, c = tid & 1;
    float ax = 0.f, ah = 0.f, bx = 0.f, bh = 0.f;
    for (int m = 0; m < H; ++m) {
        float wpu = Wp[m * 2 + c];
        float wpi = Wp[(H + m) * 2 + c];
        ax += W2[j * H + m] * wpu;
        ah += W2[(H + j) * H + m] * wpu;
        bx += W3[j * H + m] * wpi;
        bh += W3[(H + j) * H + m] * wpi;
    }
    mats[      j * 2 + c] = ax;
    mats[256 + j * 2 + c] = ah;
    mats[512 + j * 2 + c] = bx;
    mats[768 + j * 2 + c] = bh;
    if (tid < 2) {
        float s1 = 0.f, s2 = 0.f;
        for (int m = 0; m < H; ++m) {
            s1 += b2[m] * Wp[m * 2 + tid];
            s2 += b3[m] * Wp[(H + m) * 2 + tid];
        }
        mats[1024 + tid] = s1 + bp[tid];
        mats[1026 + tid] = s2;
    }
}

// ---- W -> bf16 fragment-swizzled global copy: Wsw[((k>>3)*128 + n)*8 + (k&7)]
__global__ void wswz_kernel(const float* __restrict__ W0, const float* __restrict__ W1,
                            unsigned short* __restrict__ WswU, unsigned short* __restrict__ WswI) {
    const float* W = blockIdx.x ? W1 : W0;
    unsigned short* o = blockIdx.x ? WswI : WswU;
    for (int i = threadIdx.x; i < 4096; i += 256) {
        float4 w = ((const float4*)W)[i];
        int k = i >> 5, n0 = (i & 31) * 4;
        int kb = k >> 3, kj = k & 7;
        o[(kb * 128 + n0 + 0) * 8 + kj] = f2bf(w.x);
        o[(kb * 128 + n0 + 1) * 8 + kj] = f2bf(w.y);
        o[(kb * 128 + n0 + 2) * 8 + kj] = f2bf(w.z);
        o[(kb * 128 + n0 + 3) * 8 + kj] = f2bf(w.w);
    }
}

// ---- MFMA: y = inv * (x @ W) (bf16 out) + gx = x·Mx + cv, both sides ----
// Block: 128 rows x 128 cols. LDS: Ws (32KB swizzled) + As (32KB swizzled),
// epilogue reuses LDS for padded transpose. 4 waves, each 32 rows.
__global__ __launch_bounds__(256) void mfma_node(
    const float* __restrict__ xU, const float* __restrict__ xI,
    const float* __restrict__ invU, const float* __restrict__ invI,
    const unsigned short* __restrict__ WswU, const unsigned short* __restrict__ WswI,
    unsigned short* __restrict__ yU, unsigned short* __restrict__ yI,
    const float* __restrict__ mats,
    float2* __restrict__ gxU, float2* __restrict__ gxI,
    int NU, int NI, int TU) {
    __shared__ __align__(16) unsigned short SM[32768];   // 64 KB
    unsigned short* Ws = SM;              // [kb][n][8]
    unsigned short* As = SM + 16384;      // [kb][m][8]

    bool us = blockIdx.x < (unsigned)TU;
    int tile = us ? blockIdx.x : blockIdx.x - TU;
    const float* x = us ? xU : xI;
    const float* inv = us ? invU : invI;
    const unsigned short* Wsw = us ? WswU : WswI;
    unsigned short* y = us ? yU : yI;
    const float* Mx = mats + (us ? 0 : 512);
    const float* cv = mats + (us ? 1024 : 1026);
    float2* gx = us ? gxU : gxI;
    int n = us ? NU : NI;
    int row0 = tile << 7;

    // stage W (contiguous, pre-swizzled)
    for (int i = threadIdx.x; i < 2048; i += 256)
        ((float4*)Ws)[i] = ((const float4*)Wsw)[i];
    // stage A: x -> bf16 swizzled
    for (int it = 0; it < 16; ++it) {
        int i = it * 256 + threadIdx.x;          // 0..4095
        int m = i >> 5, c4 = i & 31;
        int row = row0 + m;
        float4 v = (row < n) ? ((const float4*)x)[(size_t)row * 32 + c4]
                             : make_float4(0.f, 0.f, 0.f, 0.f);
        int k0 = c4 * 4;
        ushort4 s4; s4.x = f2bf(v.x); s4.y = f2bf(v.y); s4.z = f2bf(v.z); s4.w = f2bf(v.w);
        *(ushort4*)&As[((k0 >> 3) * 128 + m) * 8 + (k0 & 7)] = s4;
    }
    __syncthreads();

    int w = threadIdx.x >> 6, l = threadIdx.x & 63;
    int lane15 = l & 15, quad = l >> 4;

    f32x4 acc[2][8];
    #pragma unroll
    for (int rt = 0; rt < 2; ++rt)
        #pragma unroll
        for (int c = 0; c < 8; ++c) acc[rt][c] = (f32x4){0.f, 0.f, 0.f, 0.f};

    #pragma unroll
    for (int ks = 0; ks < 4; ++ks) {
        int kb = ks * 4 + quad;
        bf16x8 a0 = *(const bf16x8*)&As[(kb * 128 + w * 32 + lane15) * 8];
        bf16x8 a1 = *(const bf16x8*)&As[(kb * 128 + w * 32 + 16 + lane15) * 8];
        #pragma unroll
        for (int c = 0; c < 8; ++c) {
            bf16x8 b = *(const bf16x8*)&Ws[(kb * 128 + c * 16 + lane15) * 8];
            acc[0][c] = __builtin_amdgcn_mfma_f32_16x16x32_bf16(a0, b, acc[0][c], 0, 0, 0);
            acc[1][c] = __builtin_amdgcn_mfma_f32_16x16x32_bf16(a1, b, acc[1][c], 0, 0, 0);
        }
    }

    // gx from As (raw x in bf16): 2 threads per row (c=0/1)
    {
        int row = threadIdx.x >> 1, cc = threadIdx.x & 1;
        float p = 0.f;
        for (int kb = 0; kb < 16; ++kb) {
            const unsigned short* ap = &As[(kb * 128 + row) * 8];
            #pragma unroll
            for (int j = 0; j < 8; ++j)
                p += bfu(ap[j]) * Mx[(kb * 8 + j) * 2 + cc];
        }
        int grow = row0 + row;
        if (grow < n) ((float*)&gx[grow])[cc] = p + cv[cc];
    }
    __syncthreads();                       // all As/Ws reads done; reuse LDS

    // epilogue: scale by inv, padded LDS transpose, coalesced bf16 stores
    const int LSTR = 136;                  // ushorts per row (16B-pad)
    unsigned short* Lw = SM + w * 32 * LSTR;   // wave-private 8704 B
    #pragma unroll
    for (int rt = 0; rt < 2; ++rt) {
        #pragma unroll
        for (int r = 0; r < 4; ++r) {
            int lrow = rt * 16 + quad * 4 + r;
            int grow = row0 + w * 32 + lrow;
            float iv = (grow < n) ? inv[grow] : 0.f;
            #pragma unroll
            for (int c = 0; c < 8; ++c)
                Lw[lrow * LSTR + c * 16 + lane15] = f2bf(acc[rt][c][r] * iv);
        }
    }
    // wave-private region: per-wave LDS ordering suffices, no barrier
    #pragma unroll
    for (int pass = 0; pass < 8; ++pass) {
        int lrow = pass * 4 + quad;
        int grow = row0 + w * 32 + lrow;
        uint4 v = *(uint4*)&Lw[lrow * LSTR + lane15 * 8];
        if (grow < n) *(uint4*)&y[(size_t)grow * 128 + lane15 * 8] = v;
    }
}

// ---- gather (both sides): 16 lanes/node, uint4 rows, 4-way ILP ----------
__global__ __launch_bounds__(256) void gather_kernel(
    const int* __restrict__ offU, const int* __restrict__ valU,
    const int* __restrict__ offI, const int* __restrict__ valI,
    const unsigned short* __restrict__ yU, const unsigned short* __restrict__ yI,
    const float* __restrict__ invU, const float* __restrict__ invI,
    const float* __restrict__ b0, const float* __restrict__ b1,
    const float* __restrict__ mats,
    const float2* __restrict__ gxU, const float2* __restrict__ gxI,
    float2* __restrict__ su, float2* __restrict__ si,
    int NU, int NI, int GU) {
    bool us = blockIdx.x < (unsigned)GU;
    int nb = us ? blockIdx.x : blockIdx.x - GU;
    const int* off = us ? offU : offI;
    const int* val = us ? valU : valI;
    const unsigned short* yo = us ? yI : yU;     // neighbors are the other type
    const float* inv = us ? invU : invI;
    const float* bv = us ? b1 : b0;
    const float* Mh = mats + (us ? 256 : 768);
    const float2* gx = us ? gxU : gxI;
    float2* so = us ? su : si;
    int n = us ? NU : NI;

    int g = threadIdx.x >> 4, t = threadIdx.x & 15, j0 = t * 8;
    int u = nb * 16 + g;
    if (u >= n) return;

    float a0 = 0, a1 = 0, a2 = 0, a3 = 0, a4 = 0, a5 = 0, a6 = 0, a7 = 0;
    int k = off[u], end = off[u + 1];
    for (; k + 4 <= end; k += 4) {
        int v0 = val[k], v1 = val[k + 1], v2 = val[k + 2], v3 = val[k + 3];
        uint4 w0 = *(const uint4*)(yo + (size_t)v0 * H + j0);
        uint4 w1 = *(const uint4*)(yo + (size_t)v1 * H + j0);
        uint4 w2 = *(const uint4*)(yo + (size_t)v2 * H + j0);
        uint4 w3 = *(const uint4*)(yo + (size_t)v3 * H + j0);
        a0 += bflo(w0.x) + bflo(w1.x) + bflo(w2.x) + bflo(w3.x);
        a1 += bfhi(w0.x) + bfhi(w1.x) + bfhi(w2.x) + bfhi(w3.x);
        a2 += bflo(w0.y) + bflo(w1.y) + bflo(w2.y) + bflo(w3.y);
        a3 += bfhi(w0.y) + bfhi(w1.y) + bfhi(w2.y) + bfhi(w3.y);
        a4 += bflo(w0.z) + bflo(w1.z) + bflo(w2.z) + bflo(w3.z);
        a5 += bfhi(w0.z) + bfhi(w1.z) + bfhi(w2.z) + bfhi(w3.z);
        a6 += bflo(w0.w) + bflo(w1.w) + bflo(w2.w) + bflo(w3.w);
        a7 += bfhi(w0.w) + bfhi(w1.w) + bfhi(w2.w) + bfhi(w3.w);
    }
    for (; k < end; ++k) {
        int v0 = val[k];
        uint4 w0 = *(const uint4*)(yo + (size_t)v0 * H + j0);
        a0 += bflo(w0.x); a1 += bfhi(w0.x); a2 += bflo(w0.y); a3 += bfhi(w0.y);
        a4 += bflo(w0.z); a5 += bfhi(w0.z); a6 += bflo(w0.w); a7 += bfhi(w0.w);
    }
    float iv = inv[u];
    float4 bb0 = *(const float4*)(bv + j0), bb1 = *(const float4*)(bv + j0 + 4);
    float h0 = fmaxf(a0 * iv + bb0.x, 0.f), h1 = fmaxf(a1 * iv + bb0.y, 0.f);
    float h2 = fmaxf(a2 * iv + bb0.z, 0.f), h3 = fmaxf(a3 * iv + bb0.w, 0.f);
    float h4 = fmaxf(a4 * iv + bb1.x, 0.f), h5 = fmaxf(a5 * iv + bb1.y, 0.f);
    float h6 = fmaxf(a6 * iv + bb1.z, 0.f), h7 = fmaxf(a7 * iv + bb1.w, 0.f);
    float4 m0 = *(const float4*)(Mh + j0 * 2),      m1 = *(const float4*)(Mh + j0 * 2 + 4);
    float4 m2 = *(const float4*)(Mh + j0 * 2 + 8),  m3 = *(const float4*)(Mh + j0 * 2 + 12);
    float p0 = h0 * m0.x + h1 * m0.z + h2 * m1.x + h3 * m1.z
             + h4 * m2.x + h5 * m2.z + h6 * m3.x + h7 * m3.z;
    float p1 = h0 * m0.y + h1 * m0.w + h2 * m1.y + h3 * m1.w
             + h4 * m2.y + h5 * m2.w + h6 * m3.y + h7 * m3.w;
    #pragma unroll
    for (int o = 1; o < 16; o <<= 1) { p0 += __shfl_xor(p0, o); p1 += __shfl_xor(p1, o); }
    if (t == 0) {
        float2 gg = gx[u];
        so[u] = make_float2(p0 + gg.x, p1 + gg.y);
    }
}

__global__ void edge_kernel(const int* __restrict__ src, const int* __restrict__ dst,
                            const float2* __restrict__ su, const float2* __restrict__ si,
                            float2* __restrict__ out, int E) {
    int e0 = (blockIdx.x * 256 + threadIdx.x) * 2;
    if (e0 >= E) return;
    int2 s2 = *(const int2*)(src + e0);
    int2 d2 = *(const int2*)(dst + e0);
    float2 a = su[s2.x], b = si[d2.x];
    float l0 = a.x + b.x, l1 = a.y + b.y;
    float m = fmaxf(l0, l1);
    float q0 = __expf(l0 - m), q1 = __expf(l1 - m);
    float r = 1.0f / (q0 + q1);
    out[e0] = make_float2(q0 * r, q1 * r);
    if (e0 + 1 < E) {
        a = su[s2.y]; b = si[d2.y];
        l0 = a.x + b.x; l1 = a.y + b.y;
        m = fmaxf(l0, l1);
        q0 = __expf(l0 - m); q1 = __expf(l1 - m);
        r = 1.0f / (q0 + q1);
        out[e0 + 1] = make_float2(q0 * r, q1 * r);
    }
}

extern "C" void kernel_launch(void* const* d_in, const int* in_sizes, int n_in,
                              void* d_out, int out_size, void* d_ws, size_t ws_size,
                              hipStream_t stream) {
    const float* x_user = (const float*)d_in[0];
    const float* x_item = (const float*)d_in[1];
    const float* W0 = (const float*)d_in[2];
    const float* b0 = (const float*)d_in[3];
    const float* W1 = (const float*)d_in[4];
    const float* b1 = (const float*)d_in[5];
    const float* W2 = (const float*)d_in[6];
    const float* b2 = (const float*)d_in[7];
    const float* W3 = (const float*)d_in[8];
    const float* b3 = (const float*)d_in[9];
    const float* Wp = (const float*)d_in[10];
    const float* bp = (const float*)d_in[11];
    const int* esrc = (const int*)d_in[12];
    const int* edst = (const int*)d_in[13];

    const int NU = in_sizes[0] / H;
    const int NI = in_sizes[1] / H;
    const int E  = in_sizes[12];
    const int NBU = (NU + 127) >> 7;
    const int NBI = (NI + 127) >> 7;
    const int TU = NBU, TI = NBI;             // 128-row GEMM tiles
    const int GU = (NU + 15) >> 4, GI = (NI + 15) >> 4;

    auto rnd = [](size_t x) { return (x + 63) & ~(size_t)63; };
    char* base = (char*)d_ws;
    size_t o = 0;
    auto alloc = [&](size_t elems) { void* p = base + o * 4; o += rnd(elems); return p; };

    float* inv_du = (float*)alloc(NU);
    float* inv_di = (float*)alloc(NI);
    float2* su    = (float2*)alloc((size_t)NU * 2);
    float2* si    = (float2*)alloc((size_t)NI * 2);
    float2* gxU   = (float2*)alloc((size_t)NU * 2);
    float2* gxI   = (float2*)alloc((size_t)NI * 2);
    float* mats   = (float*)alloc(1056);
    size_t hist_off = o;
    int* histU = (int*)alloc(1024);
    int* histI = (int*)alloc(512);
    size_t hist_words = o - hist_off;
    int* bOffU = (int*)alloc(NBU + 1);
    int* bOffI = (int*)alloc(NBI + 1);
    int* curU  = (int*)alloc(NBU);
    int* curI  = (int*)alloc(NBI);
    int* offU  = (int*)alloc(NU + 1);
    int* offI  = (int*)alloc(NI + 1);
    int* valU  = (int*)alloc(E);
    int* valI  = (int*)alloc(E);
    unsigned* pairU = (unsigned*)alloc(E);
    unsigned* pairI = (unsigned*)alloc(E);
    unsigned short* WswU = (unsigned short*)alloc(8192);   // 16384 bf16
    unsigned short* WswI = (unsigned short*)alloc(8192);
    unsigned short* yU = (unsigned short*)alloc((size_t)NU * 64);
    unsigned short* yI = (unsigned short*)alloc((size_t)NI * 64);

    hipMemsetAsync(histU, 0, hist_words * 4, stream);

    fold_kernel<<<1, 256, 0, stream>>>(W2, b2, W3, b3, Wp, bp, mats);
    wswz_kernel<<<2, 256, 0, stream>>>(W0, W1, WswU, WswI);

    p0_hist<<<256, 256, 0, stream>>>(esrc, edst, histU, histI, E, NBU, NBI);
    p_scan<<<1, 1024, 0, stream>>>(histU, histI, bOffU, bOffI, curU, curI, NBU, NBI, E);
    p1_partition<<<(E + 4095) / 4096, 256, 0, stream>>>(
        esrc, edst, curU, curI, pairU, pairI, E, NBU, NBI);
    p2_build<<<NBU, 256, 0, stream>>>(pairU, bOffU, offU, inv_du, valU, NU, E);
    p2_build<<<NBI, 256, 0, stream>>>(pairI, bOffI, offI, inv_di, valI, NI, E);

    // yU = inv_du*(x_user@W0); yI = inv_di*(x_item@W1); gx fused
    mfma_node<<<TU + TI, 256, 0, stream>>>(
        x_user, x_item, inv_du, inv_di, WswU, WswI, yU, yI, mats, gxU, gxI, NU, NI, TU);

    gather_kernel<<<GU + GI, 256, 0, stream>>>(
        offU, valU, offI, valI, yU, yI, inv_du, inv_di, b0, b1, mats,
        gxU, gxI, su, si, NU, NI, GU);

    edge_kernel<<<(E / 2 + 255) / 256, 256, 0, stream>>>(esrc, edst, su, si, (float2*)d_out, E);
}

// Round 5
// 310.294 us; speedup vs baseline: 12.0243x; 1.0732x over previous
//
#include <hip/hip_runtime.h>
#include <hip/hip_bf16.h>

// GraphConv x2 + per-type linear + edge MLP + softmax(2).
// R5: (a) adjacency coarsely sorted by neighbor id (8-way sub-bucket counting
//     sort in p2) so concurrent gather blocks sweep y in sync -> L2-window
//     locality; (b) padded-bucket sort (no p0 hist / no global scan);
//     (c) merged prep + merged p2; 7 dispatches total.

#define H 128
#define CAPU 1536
#define CAPI 3072

typedef __attribute__((ext_vector_type(8))) short bf16x8;
typedef __attribute__((ext_vector_type(4))) float f32x4;

__device__ __forceinline__ unsigned short f2bf(float f) {
    unsigned u = __float_as_uint(f);
    unsigned r = (u + 0x7fffu + ((u >> 16) & 1u)) >> 16;   // RNE
    return (unsigned short)r;
}
__device__ __forceinline__ float bflo(unsigned b) { return __uint_as_float(b << 16); }
__device__ __forceinline__ float bfhi(unsigned b) { return __uint_as_float(b & 0xffff0000u); }
__device__ __forceinline__ float bfu(unsigned short b) { return __uint_as_float((unsigned)b << 16); }

// ---- P1: partition edges into padded buckets (zero-init global cursors) ----
// pairX[CAP*b + cursor] = (node&127)<<24 | other_node
__global__ __launch_bounds__(256) void p1_partition(
    const int* __restrict__ src, const int* __restrict__ dst,
    int* __restrict__ gCurU, int* __restrict__ gCurI,
    unsigned* __restrict__ pairU, unsigned* __restrict__ pairI,
    int E, int nbu, int nbi) {
    __shared__ int cntU[1024], baseU[1024], cntI[512], baseI[512];
    int t0 = blockIdx.x * 2048;
    for (int i = threadIdx.x; i < nbu; i += 256) cntU[i] = 0;
    for (int i = threadIdx.x; i < nbi; i += 256) cntI[i] = 0;
    __syncthreads();
    #pragma unroll
    for (int j = 0; j < 8; ++j) {
        int e = t0 + j * 256 + threadIdx.x;
        if (e < E) { atomicAdd(&cntU[src[e] >> 7], 1); atomicAdd(&cntI[dst[e] >> 7], 1); }
    }
    __syncthreads();
    for (int i = threadIdx.x; i < nbu; i += 256) {
        int c = cntU[i];
        baseU[i] = c ? (CAPU * i + atomicAdd(&gCurU[i], c)) : 0;
    }
    for (int i = threadIdx.x; i < nbi; i += 256) {
        int c = cntI[i];
        baseI[i] = c ? (CAPI * i + atomicAdd(&gCurI[i], c)) : 0;
    }
    __syncthreads();
    #pragma unroll
    for (int j = 0; j < 8; ++j) {
        int e = t0 + j * 256 + threadIdx.x;
        if (e < E) {
            int s = src[e], d = dst[e];
            int bu = s >> 7, bi = d >> 7;
            int r1 = atomicSub(&cntU[bu], 1) - 1;
            int idx1 = baseU[bu] + r1;
            if (idx1 < CAPU * (bu + 1))
                pairU[idx1] = ((unsigned)(s & 127) << 24) | (unsigned)d;
            int r2 = atomicSub(&cntI[bi], 1) - 1;
            int idx2 = baseI[bi] + r2;
            if (idx2 < CAPI * (bi + 1))
                pairI[idx2] = ((unsigned)(d & 127) << 24) | (unsigned)s;
        }
    }
}

// ---- P2 (both sides): per-bucket counting sort by (node, neighbor>>shift) ----
// Produces adjacency coarsely sorted by neighbor id, per-node (start,end), inv.
__global__ __launch_bounds__(256) void p2_build(
    const unsigned* __restrict__ pairU, const unsigned* __restrict__ pairI,
    const int* __restrict__ gCurU, const int* __restrict__ gCurI,
    int2* __restrict__ offU, int2* __restrict__ offI,
    float* __restrict__ invU, float* __restrict__ invI,
    int* __restrict__ valU, int* __restrict__ valI,
    int NU, int NI, int NBU, int shiftU, int shiftI) {
    __shared__ int cnt[1024], pref[1024], part[256];
    __shared__ int out[CAPI];
    bool us = blockIdx.x < (unsigned)NBU;
    int b = us ? blockIdx.x : blockIdx.x - NBU;
    const unsigned* pairs = us ? pairU : pairI;
    int cap = us ? CAPU : CAPI;
    int size = us ? gCurU[b] : gCurI[b];
    if (size > cap) size = cap;
    int start = b * cap;
    int shift = us ? shiftU : shiftI;
    int2* off = us ? offU : offI;
    float* inv = us ? invU : invI;
    int* val = us ? valU : valI;
    int n = us ? NU : NI;
    int t = threadIdx.x;

    for (int i = t; i < 1024; i += 256) cnt[i] = 0;
    __syncthreads();
    for (int i = t; i < size; i += 256) {
        unsigned p = pairs[start + i];
        int key = (int)((p >> 24) << 3) | (int)((p & 0xFFFFFFu) >> shift);
        atomicAdd(&cnt[key], 1);
    }
    __syncthreads();
    // exclusive scan over 1024 keys: serial-4 + 256-way LDS scan
    int b4 = t * 4;
    int s0 = cnt[b4], s1 = cnt[b4 + 1], s2 = cnt[b4 + 2], s3 = cnt[b4 + 3];
    int tot = s0 + s1 + s2 + s3;
    part[t] = tot; __syncthreads();
    for (int o2 = 1; o2 < 256; o2 <<= 1) {
        int v = (t >= o2) ? part[t - o2] : 0; __syncthreads();
        part[t] += v; __syncthreads();
    }
    int excl = part[t] - tot;
    pref[b4] = excl;
    pref[b4 + 1] = excl + s0;
    pref[b4 + 2] = excl + s0 + s1;
    pref[b4 + 3] = excl + s0 + s1 + s2;
    __syncthreads();
    if (t < 128) {
        int node = (b << 7) + t;
        if (node < n) {
            int st = pref[t * 8];
            int en = (t == 127) ? size : pref[t * 8 + 8];
            off[node] = make_int2(start + st, start + en);
            inv[node] = rsqrtf(fmaxf((float)(en - st), 1.0f));
        }
    }
    __syncthreads();
    for (int i = t; i < size; i += 256) {       // bin (pref doubles as cursor)
        unsigned p = pairs[start + i];
        int key = (int)((p >> 24) << 3) | (int)((p & 0xFFFFFFu) >> shift);
        int r = atomicAdd(&pref[key], 1);
        out[r] = (int)(p & 0xFFFFFFu);
    }
    __syncthreads();
    for (int i = t; i < size; i += 256) val[start + i] = out[i];
}

// ---- prep: fold mats (block 0) + W swizzle (blocks 1,2) -----------------
// mats layout: Ax[256] | Ah[256] | Bx[256] | Bh[256] | cu[2] | ci[2]
__global__ void prep_kernel(const float* __restrict__ W0, const float* __restrict__ W1,
                            const float* __restrict__ W2, const float* __restrict__ b2,
                            const float* __restrict__ W3, const float* __restrict__ b3,
                            const float* __restrict__ Wp, const float* __restrict__ bp,
                            float* __restrict__ mats,
                            unsigned short* __restrict__ WswU, unsigned short* __restrict__ WswI) {
    if (blockIdx.x == 0) {
        int tid = threadIdx.x;
        int j = tid >> 1, c = tid & 1;
        float ax = 0.f, ah = 0.f, bx = 0.f, bh = 0.f;
        for (int m = 0; m < H; ++m) {
            float wpu = Wp[m * 2 + c];
            float wpi = Wp[(H + m) * 2 + c];
            ax += W2[j * H + m] * wpu;
            ah += W2[(H + j) * H + m] * wpu;
            bx += W3[j * H + m] * wpi;
            bh += W3[(H + j) * H + m] * wpi;
        }
        mats[      j * 2 + c] = ax;
        mats[256 + j * 2 + c] = ah;
        mats[512 + j * 2 + c] = bx;
        mats[768 + j * 2 + c] = bh;
        if (tid < 2) {
            float s1 = 0.f, s2 = 0.f;
            for (int m = 0; m < H; ++m) {
                s1 += b2[m] * Wp[m * 2 + tid];
                s2 += b3[m] * Wp[(H + m) * 2 + tid];
            }
            mats[1024 + tid] = s1 + bp[tid];
            mats[1026 + tid] = s2;
        }
    } else {
        const float* W = (blockIdx.x == 1) ? W0 : W1;
        unsigned short* o = (blockIdx.x == 1) ? WswU : WswI;
        for (int i = threadIdx.x; i < 4096; i += 256) {
            float4 w = ((const float4*)W)[i];
            int k = i >> 5, n0 = (i & 31) * 4;
            int kb = k >> 3, kj = k & 7;
            o[(kb * 128 + n0 + 0) * 8 + kj] = f2bf(w.x);
            o[(kb * 128 + n0 + 1) * 8 + kj] = f2bf(w.y);
            o[(kb * 128 + n0 + 2) * 8 + kj] = f2bf(w.z);
            o[(kb * 128 + n0 + 3) * 8 + kj] = f2bf(w.w);
        }
    }
}

// ---- MFMA: y = inv * (x @ W) (bf16 out) + gx = x·Mx + cv, both sides ----
__global__ __launch_bounds__(256) void mfma_node(
    const float* __restrict__ xU, const float* __restrict__ xI,
    const float* __restrict__ invU, const float* __restrict__ invI,
    const unsigned short* __restrict__ WswU, const unsigned short* __restrict__ WswI,
    unsigned short* __restrict__ yU, unsigned short* __restrict__ yI,
    const float* __restrict__ mats,
    float2* __restrict__ gxU, float2* __restrict__ gxI,
    int NU, int NI, int TU) {
    __shared__ __align__(16) unsigned short SM[32768];   // 64 KB
    unsigned short* Ws = SM;              // [kb][n][8]
    unsigned short* As = SM + 16384;      // [kb][m][8]

    bool us = blockIdx.x < (unsigned)TU;
    int tile = us ? blockIdx.x : blockIdx.x - TU;
    const float* x = us ? xU : xI;
    const float* inv = us ? invU : invI;
    const unsigned short* Wsw = us ? WswU : WswI;
    unsigned short* y = us ? yU : yI;
    const float* Mx = mats + (us ? 0 : 512);
    const float* cv = mats + (us ? 1024 : 1026);
    float2* gx = us ? gxU : gxI;
    int n = us ? NU : NI;
    int row0 = tile << 7;

    for (int i = threadIdx.x; i < 2048; i += 256)
        ((float4*)Ws)[i] = ((const float4*)Wsw)[i];
    for (int it = 0; it < 16; ++it) {
        int i = it * 256 + threadIdx.x;
        int m = i >> 5, c4 = i & 31;
        int row = row0 + m;
        float4 v = (row < n) ? ((const float4*)x)[(size_t)row * 32 + c4]
                             : make_float4(0.f, 0.f, 0.f, 0.f);
        int k0 = c4 * 4;
        ushort4 s4; s4.x = f2bf(v.x); s4.y = f2bf(v.y); s4.z = f2bf(v.z); s4.w = f2bf(v.w);
        *(ushort4*)&As[((k0 >> 3) * 128 + m) * 8 + (k0 & 7)] = s4;
    }
    __syncthreads();

    int w = threadIdx.x >> 6, l = threadIdx.x & 63;
    int lane15 = l & 15, quad = l >> 4;

    f32x4 acc[2][8];
    #pragma unroll
    for (int rt = 0; rt < 2; ++rt)
        #pragma unroll
        for (int c = 0; c < 8; ++c) acc[rt][c] = (f32x4){0.f, 0.f, 0.f, 0.f};

    #pragma unroll
    for (int ks = 0; ks < 4; ++ks) {
        int kb = ks * 4 + quad;
        bf16x8 a0 = *(const bf16x8*)&As[(kb * 128 + w * 32 + lane15) * 8];
        bf16x8 a1 = *(const bf16x8*)&As[(kb * 128 + w * 32 + 16 + lane15) * 8];
        #pragma unroll
        for (int c = 0; c < 8; ++c) {
            bf16x8 b = *(const bf16x8*)&Ws[(kb * 128 + c * 16 + lane15) * 8];
            acc[0][c] = __builtin_amdgcn_mfma_f32_16x16x32_bf16(a0, b, acc[0][c], 0, 0, 0);
            acc[1][c] = __builtin_amdgcn_mfma_f32_16x16x32_bf16(a1, b, acc[1][c], 0, 0, 0);
        }
    }

    {   // gx from As (bf16 x): 2 threads per row
        int row = threadIdx.x >> 1, cc = threadIdx.x & 1;
        float p = 0.f;
        for (int kb = 0; kb < 16; ++kb) {
            const unsigned short* ap = &As[(kb * 128 + row) * 8];
            #pragma unroll
            for (int j = 0; j < 8; ++j)
                p += bfu(ap[j]) * Mx[(kb * 8 + j) * 2 + cc];
        }
        int grow = row0 + row;
        if (grow < n) ((float*)&gx[grow])[cc] = p + cv[cc];
    }
    __syncthreads();

    const int LSTR = 136;
    unsigned short* Lw = SM + w * 32 * LSTR;
    #pragma unroll
    for (int rt = 0; rt < 2; ++rt) {
        #pragma unroll
        for (int r = 0; r < 4; ++r) {
            int lrow = rt * 16 + quad * 4 + r;
            int grow = row0 + w * 32 + lrow;
            float iv = (grow < n) ? inv[grow] : 0.f;
            #pragma unroll
            for (int c = 0; c < 8; ++c)
                Lw[lrow * LSTR + c * 16 + lane15] = f2bf(acc[rt][c][r] * iv);
        }
    }
    #pragma unroll
    for (int pass = 0; pass < 8; ++pass) {
        int lrow = pass * 4 + quad;
        int grow = row0 + w * 32 + lrow;
        uint4 v = *(uint4*)&Lw[lrow * LSTR + lane15 * 8];
        if (grow < n) *(uint4*)&y[(size_t)grow * 128 + lane15 * 8] = v;
    }
}

// ---- gather (both sides): 16 lanes/node, uint4 rows, 4-way ILP ----------
__global__ __launch_bounds__(256) void gather_kernel(
    const int2* __restrict__ offU, const int* __restrict__ valU,
    const int2* __restrict__ offI, const int* __restrict__ valI,
    const unsigned short* __restrict__ yU, const unsigned short* __restrict__ yI,
    const float* __restrict__ invU, const float* __restrict__ invI,
    const float* __restrict__ b0, const float* __restrict__ b1,
    const float* __restrict__ mats,
    const float2* __restrict__ gxU, const float2* __restrict__ gxI,
    float2* __restrict__ su, float2* __restrict__ si,
    int NU, int NI, int GU) {
    bool us = blockIdx.x < (unsigned)GU;
    int nb = us ? blockIdx.x : blockIdx.x - GU;
    const int2* off = us ? offU : offI;
    const int* val = us ? valU : valI;
    const unsigned short* yo = us ? yI : yU;
    const float* inv = us ? invU : invI;
    const float* bv = us ? b1 : b0;
    const float* Mh = mats + (us ? 256 : 768);
    const float2* gx = us ? gxU : gxI;
    float2* so = us ? su : si;
    int n = us ? NU : NI;

    int g = threadIdx.x >> 4, t = threadIdx.x & 15, j0 = t * 8;
    int u = nb * 16 + g;
    if (u >= n) return;

    float a0 = 0, a1 = 0, a2 = 0, a3 = 0, a4 = 0, a5 = 0, a6 = 0, a7 = 0;
    int2 oe = off[u];
    int k = oe.x, end = oe.y;
    for (; k + 4 <= end; k += 4) {
        int v0 = val[k], v1 = val[k + 1], v2 = val[k + 2], v3 = val[k + 3];
        uint4 w0 = *(const uint4*)(yo + (size_t)v0 * H + j0);
        uint4 w1 = *(const uint4*)(yo + (size_t)v1 * H + j0);
        uint4 w2 = *(const uint4*)(yo + (size_t)v2 * H + j0);
        uint4 w3 = *(const uint4*)(yo + (size_t)v3 * H + j0);
        a0 += bflo(w0.x) + bflo(w1.x) + bflo(w2.x) + bflo(w3.x);
        a1 += bfhi(w0.x) + bfhi(w1.x) + bfhi(w2.x) + bfhi(w3.x);
        a2 += bflo(w0.y) + bflo(w1.y) + bflo(w2.y) + bflo(w3.y);
        a3 += bfhi(w0.y) + bfhi(w1.y) + bfhi(w2.y) + bfhi(w3.y);
        a4 += bflo(w0.z) + bflo(w1.z) + bflo(w2.z) + bflo(w3.z);
        a5 += bfhi(w0.z) + bfhi(w1.z) + bfhi(w2.z) + bfhi(w3.z);
        a6 += bflo(w0.w) + bflo(w1.w) + bflo(w2.w) + bflo(w3.w);
        a7 += bfhi(w0.w) + bfhi(w1.w) + bfhi(w2.w) + bfhi(w3.w);
    }
    for (; k < end; ++k) {
        int v0 = val[k];
        uint4 w0 = *(const uint4*)(yo + (size_t)v0 * H + j0);
        a0 += bflo(w0.x); a1 += bfhi(w0.x); a2 += bflo(w0.y); a3 += bfhi(w0.y);
        a4 += bflo(w0.z); a5 += bfhi(w0.z); a6 += bflo(w0.w); a7 += bfhi(w0.w);
    }
    float iv = inv[u];
    float4 bb0 = *(const float4*)(bv + j0), bb1 = *(const float4*)(bv + j0 + 4);
    float h0 = fmaxf(a0 * iv + bb0.x, 0.f), h1 = fmaxf(a1 * iv + bb0.y, 0.f);
    float h2 = fmaxf(a2 * iv + bb0.z, 0.f), h3 = fmaxf(a3 * iv + bb0.w, 0.f);
    float h4 = fmaxf(a4 * iv + bb1.x, 0.f), h5 = fmaxf(a5 * iv + bb1.y, 0.f);
    float h6 = fmaxf(a6 * iv + bb1.z, 0.f), h7 = fmaxf(a7 * iv + bb1.w, 0.f);
    float4 m0 = *(const float4*)(Mh + j0 * 2),      m1 = *(const float4*)(Mh + j0 * 2 + 4);
    float4 m2 = *(const float4*)(Mh + j0 * 2 + 8),  m3 = *(const float4*)(Mh + j0 * 2 + 12);
    float p0 = h0 * m0.x + h1 * m0.z + h2 * m1.x + h3 * m1.z
             + h4 * m2.x + h5 * m2.z + h6 * m3.x + h7 * m3.z;
    float p1 = h0 * m0.y + h1 * m0.w + h2 * m1.y + h3 * m1.w
             + h4 * m2.y + h5 * m2.w + h6 * m3.y + h7 * m3.w;
    #pragma unroll
    for (int o = 1; o < 16; o <<= 1) { p0 += __shfl_xor(p0, o); p1 += __shfl_xor(p1, o); }
    if (t == 0) {
        float2 gg = gx[u];
        so[u] = make_float2(p0 + gg.x, p1 + gg.y);
    }
}

__global__ void edge_kernel(const int* __restrict__ src, const int* __restrict__ dst,
                            const float2* __restrict__ su, const float2* __restrict__ si,
                            float2* __restrict__ out, int E) {
    int e0 = (blockIdx.x * 256 + threadIdx.x) * 2;
    if (e0 >= E) return;
    int2 s2 = *(const int2*)(src + e0);
    int2 d2 = *(const int2*)(dst + e0);
    float2 a = su[s2.x], b = si[d2.x];
    float l0 = a.x + b.x, l1 = a.y + b.y;
    float m = fmaxf(l0, l1);
    float q0 = __expf(l0 - m), q1 = __expf(l1 - m);
    float r = 1.0f / (q0 + q1);
    out[e0] = make_float2(q0 * r, q1 * r);
    if (e0 + 1 < E) {
        a = su[s2.y]; b = si[d2.y];
        l0 = a.x + b.x; l1 = a.y + b.y;
        m = fmaxf(l0, l1);
        q0 = __expf(l0 - m); q1 = __expf(l1 - m);
        r = 1.0f / (q0 + q1);
        out[e0 + 1] = make_float2(q0 * r, q1 * r);
    }
}

extern "C" void kernel_launch(void* const* d_in, const int* in_sizes, int n_in,
                              void* d_out, int out_size, void* d_ws, size_t ws_size,
                              hipStream_t stream) {
    const float* x_user = (const float*)d_in[0];
    const float* x_item = (const float*)d_in[1];
    const float* W0 = (const float*)d_in[2];
    const float* b0 = (const float*)d_in[3];
    const float* W1 = (const float*)d_in[4];
    const float* b1 = (const float*)d_in[5];
    const float* W2 = (const float*)d_in[6];
    const float* b2 = (const float*)d_in[7];
    const float* W3 = (const float*)d_in[8];
    const float* b3 = (const float*)d_in[9];
    const float* Wp = (const float*)d_in[10];
    const float* bp = (const float*)d_in[11];
    const int* esrc = (const int*)d_in[12];
    const int* edst = (const int*)d_in[13];

    const int NU = in_sizes[0] / H;
    const int NI = in_sizes[1] / H;
    const int E  = in_sizes[12];
    const int NBU = (NU + 127) >> 7;
    const int NBI = (NI + 127) >> 7;
    const int GU = (NU + 15) >> 4, GI = (NI + 15) >> 4;
    // sub-bucket shifts: top-3 bits of the neighbor id's range
    auto topshift = [](int n) {
        int bits = 32 - __builtin_clz((unsigned)(n - 1));
        return bits > 3 ? bits - 3 : 0;
    };
    const int shiftU = topshift(NI);   // user adjacency holds item ids
    const int shiftI = topshift(NU);   // item adjacency holds user ids

    auto rnd = [](size_t x) { return (x + 63) & ~(size_t)63; };
    char* base = (char*)d_ws;
    size_t o = 0;
    auto alloc = [&](size_t elems) { void* p = base + o * 4; o += rnd(elems); return p; };

    float* inv_du = (float*)alloc(NU);
    float* inv_di = (float*)alloc(NI);
    float2* su    = (float2*)alloc((size_t)NU * 2);
    float2* si    = (float2*)alloc((size_t)NI * 2);
    float2* gxU   = (float2*)alloc((size_t)NU * 2);
    float2* gxI   = (float2*)alloc((size_t)NI * 2);
    float* mats   = (float*)alloc(1056);
    size_t cur_off = o;                         // cursors contiguous, one memset
    int* gCurU = (int*)alloc(NBU);
    int* gCurI = (int*)alloc(NBI);
    size_t cur_words = o - cur_off;
    int2* offU = (int2*)alloc((size_t)NU * 2);
    int2* offI = (int2*)alloc((size_t)NI * 2);
    int* valU  = (int*)alloc((size_t)NBU * CAPU);
    int* valI  = (int*)alloc((size_t)NBI * CAPI);
    unsigned* pairU = (unsigned*)alloc((size_t)NBU * CAPU);
    unsigned* pairI = (unsigned*)alloc((size_t)NBI * CAPI);
    unsigned short* WswU = (unsigned short*)alloc(8192);
    unsigned short* WswI = (unsigned short*)alloc(8192);
    unsigned short* yU = (unsigned short*)alloc((size_t)NU * 64);
    unsigned short* yI = (unsigned short*)alloc((size_t)NI * 64);

    hipMemsetAsync(gCurU, 0, cur_words * 4, stream);

    prep_kernel<<<3, 256, 0, stream>>>(W0, W1, W2, b2, W3, b3, Wp, bp, mats, WswU, WswI);

    p1_partition<<<(E + 2047) / 2048, 256, 0, stream>>>(
        esrc, edst, gCurU, gCurI, pairU, pairI, E, NBU, NBI);
    p2_build<<<NBU + NBI, 256, 0, stream>>>(
        pairU, pairI, gCurU, gCurI, offU, offI, inv_du, inv_di, valU, valI,
        NU, NI, NBU, shiftU, shiftI);

    mfma_node<<<NBU + NBI, 256, 0, stream>>>(
        x_user, x_item, inv_du, inv_di, WswU, WswI, yU, yI, mats, gxU, gxI, NU, NI, NBU);

    gather_kernel<<<GU + GI, 256, 0, stream>>>(
        offU, valU, offI, valI, yU, yI, inv_du, inv_di, b0, b1, mats,
        gxU, gxI, su, si, NU, NI, GU);

    edge_kernel<<<(E / 2 + 255) / 256, 256, 0, stream>>>(esrc, edst, su, si, (float2*)d_out, E);
}

// Round 6
// 303.123 us; speedup vs baseline: 12.3088x; 1.0237x over previous
//
#include <hip/hip_runtime.h>
#include <hip/hip_bf16.h>

// GraphConv x2 + per-type linear + edge MLP + softmax(2).
// R6: pipeline fusion. K1 = fold + W-swizzle + p1 (disjoint blocks).
//     K2 = p2 (CSR build) UNION mfma (y = x@W unscaled, B-frags from global,
//     LDS 34.8 KB) -- independent phases overlap on the machine because inv
//     scaling is deferred to the gather (per-neighbor fma, same VALU count).
//     5 dispatches total (was 7).

#define H 128
#define CAPU 1536
#define CAPI 3072

typedef __attribute__((ext_vector_type(8))) short bf16x8;
typedef __attribute__((ext_vector_type(4))) float f32x4;

__device__ __forceinline__ unsigned short f2bf(float f) {
    unsigned u = __float_as_uint(f);
    unsigned r = (u + 0x7fffu + ((u >> 16) & 1u)) >> 16;   // RNE
    return (unsigned short)r;
}
__device__ __forceinline__ float bflo(unsigned b) { return __uint_as_float(b << 16); }
__device__ __forceinline__ float bfhi(unsigned b) { return __uint_as_float(b & 0xffff0000u); }
__device__ __forceinline__ float bfu(unsigned short b) { return __uint_as_float((unsigned)b << 16); }

// ==== K1: block0 = fold mats; blocks1-2 = W swizzle; blocks3+ = p1 partition
// mats layout: Ax[256] | Ah[256] | Bx[256] | Bh[256] | cu[2] | ci[2]
__global__ __launch_bounds__(256) void k1_prep_p1(
    const float* __restrict__ W0, const float* __restrict__ W1,
    const float* __restrict__ W2, const float* __restrict__ b2,
    const float* __restrict__ W3, const float* __restrict__ b3,
    const float* __restrict__ Wp, const float* __restrict__ bp,
    float* __restrict__ mats,
    unsigned short* __restrict__ WswU, unsigned short* __restrict__ WswI,
    const int* __restrict__ src, const int* __restrict__ dst,
    int* __restrict__ gCurU, int* __restrict__ gCurI,
    unsigned* __restrict__ pairU, unsigned* __restrict__ pairI,
    int E, int nbu, int nbi) {
    __shared__ int cntU[1024], baseU[1024], cntI[512], baseI[512];
    int bx = blockIdx.x;
    if (bx == 0) {
        int tid = threadIdx.x;
        int j = tid >> 1, c = tid & 1;
        float ax = 0.f, ah = 0.f, bx2 = 0.f, bh = 0.f;
        for (int m = 0; m < H; ++m) {
            float wpu = Wp[m * 2 + c];
            float wpi = Wp[(H + m) * 2 + c];
            ax += W2[j * H + m] * wpu;
            ah += W2[(H + j) * H + m] * wpu;
            bx2 += W3[j * H + m] * wpi;
            bh += W3[(H + j) * H + m] * wpi;
        }
        mats[      j * 2 + c] = ax;
        mats[256 + j * 2 + c] = ah;
        mats[512 + j * 2 + c] = bx2;
        mats[768 + j * 2 + c] = bh;
        if (tid < 2) {
            float s1 = 0.f, s2 = 0.f;
            for (int m = 0; m < H; ++m) {
                s1 += b2[m] * Wp[m * 2 + tid];
                s2 += b3[m] * Wp[(H + m) * 2 + tid];
            }
            mats[1024 + tid] = s1 + bp[tid];
            mats[1026 + tid] = s2;
        }
        return;
    }
    if (bx <= 2) {
        const float* W = (bx == 1) ? W0 : W1;
        unsigned short* o = (bx == 1) ? WswU : WswI;
        for (int i = threadIdx.x; i < 4096; i += 256) {
            float4 w = ((const float4*)W)[i];
            int k = i >> 5, n0 = (i & 31) * 4;
            int kb = k >> 3, kj = k & 7;
            o[(kb * 128 + n0 + 0) * 8 + kj] = f2bf(w.x);
            o[(kb * 128 + n0 + 1) * 8 + kj] = f2bf(w.y);
            o[(kb * 128 + n0 + 2) * 8 + kj] = f2bf(w.z);
            o[(kb * 128 + n0 + 3) * 8 + kj] = f2bf(w.w);
        }
        return;
    }
    // ---- p1 partition: pairX[CAP*b + cursor] = (node&127)<<24 | other ----
    int t0 = (bx - 3) * 2048;
    for (int i = threadIdx.x; i < nbu; i += 256) cntU[i] = 0;
    for (int i = threadIdx.x; i < nbi; i += 256) cntI[i] = 0;
    __syncthreads();
    #pragma unroll
    for (int j = 0; j < 8; ++j) {
        int e = t0 + j * 256 + threadIdx.x;
        if (e < E) { atomicAdd(&cntU[src[e] >> 7], 1); atomicAdd(&cntI[dst[e] >> 7], 1); }
    }
    __syncthreads();
    for (int i = threadIdx.x; i < nbu; i += 256) {
        int c = cntU[i];
        baseU[i] = c ? (CAPU * i + atomicAdd(&gCurU[i], c)) : 0;
    }
    for (int i = threadIdx.x; i < nbi; i += 256) {
        int c = cntI[i];
        baseI[i] = c ? (CAPI * i + atomicAdd(&gCurI[i], c)) : 0;
    }
    __syncthreads();
    #pragma unroll
    for (int j = 0; j < 8; ++j) {
        int e = t0 + j * 256 + threadIdx.x;
        if (e < E) {
            int s = src[e], d = dst[e];
            int bu = s >> 7, bi = d >> 7;
            int r1 = atomicSub(&cntU[bu], 1) - 1;
            int idx1 = baseU[bu] + r1;
            if (idx1 < CAPU * (bu + 1))
                pairU[idx1] = ((unsigned)(s & 127) << 24) | (unsigned)d;
            int r2 = atomicSub(&cntI[bi], 1) - 1;
            int idx2 = baseI[bi] + r2;
            if (idx2 < CAPI * (bi + 1))
                pairI[idx2] = ((unsigned)(d & 127) << 24) | (unsigned)s;
        }
    }
}

// ==== K2: blocks [0, NBU+NBI) = p2 CSR build; rest = mfma y/gx ===========
__global__ __launch_bounds__(256) void k2_build_mfma(
    const unsigned* __restrict__ pairU, const unsigned* __restrict__ pairI,
    const int* __restrict__ gCurU, const int* __restrict__ gCurI,
    int2* __restrict__ offU, int2* __restrict__ offI,
    float* __restrict__ invU, float* __restrict__ invI,
    int* __restrict__ valU, int* __restrict__ valI,
    const float* __restrict__ xU, const float* __restrict__ xI,
    const unsigned short* __restrict__ WswU, const unsigned short* __restrict__ WswI,
    unsigned short* __restrict__ yU, unsigned short* __restrict__ yI,
    const float* __restrict__ mats,
    float2* __restrict__ gxU, float2* __restrict__ gxI,
    int NU, int NI, int NBU, int NBI, int shiftU, int shiftI) {
    __shared__ __align__(16) char SMEM[34816];
    int nP2 = NBU + NBI;
    int t = threadIdx.x;

    if (blockIdx.x < (unsigned)nP2) {
        // ---- p2: per-bucket counting sort by (node, neighbor>>shift) ----
        int* cnt  = (int*)SMEM;          // 1024
        int* pref = cnt + 1024;          // 1024
        int* part = pref + 1024;         // 256
        int* out  = part + 256;          // up to CAPI
        bool us = blockIdx.x < (unsigned)NBU;
        int b = us ? blockIdx.x : blockIdx.x - NBU;
        const unsigned* pairs = us ? pairU : pairI;
        int cap = us ? CAPU : CAPI;
        int size = us ? gCurU[b] : gCurI[b];
        if (size > cap) size = cap;
        int start = b * cap;
        int shift = us ? shiftU : shiftI;
        int2* off = us ? offU : offI;
        float* inv = us ? invU : invI;
        int* val = us ? valU : valI;
        int n = us ? NU : NI;

        for (int i = t; i < 1024; i += 256) cnt[i] = 0;
        __syncthreads();
        for (int i = t; i < size; i += 256) {
            unsigned p = pairs[start + i];
            int key = (int)((p >> 24) << 3) | (int)((p & 0xFFFFFFu) >> shift);
            atomicAdd(&cnt[key], 1);
        }
        __syncthreads();
        int b4 = t * 4;
        int s0 = cnt[b4], s1 = cnt[b4 + 1], s2 = cnt[b4 + 2], s3 = cnt[b4 + 3];
        int tot = s0 + s1 + s2 + s3;
        part[t] = tot; __syncthreads();
        for (int o2 = 1; o2 < 256; o2 <<= 1) {
            int v = (t >= o2) ? part[t - o2] : 0; __syncthreads();
            part[t] += v; __syncthreads();
        }
        int excl = part[t] - tot;
        pref[b4] = excl;
        pref[b4 + 1] = excl + s0;
        pref[b4 + 2] = excl + s0 + s1;
        pref[b4 + 3] = excl + s0 + s1 + s2;
        __syncthreads();
        if (t < 128) {
            int node = (b << 7) + t;
            if (node < n) {
                int st = pref[t * 8];
                int en = (t == 127) ? size : pref[t * 8 + 8];
                off[node] = make_int2(start + st, start + en);
                inv[node] = rsqrtf(fmaxf((float)(en - st), 1.0f));
            }
        }
        __syncthreads();
        for (int i = t; i < size; i += 256) {
            unsigned p = pairs[start + i];
            int key = (int)((p >> 24) << 3) | (int)((p & 0xFFFFFFu) >> shift);
            int r = atomicAdd(&pref[key], 1);
            out[r] = (int)(p & 0xFFFFFFu);
        }
        __syncthreads();
        for (int i = t; i < size; i += 256) val[start + i] = out[i];
        return;
    }

    // ---- mfma: y = x @ W (bf16, UNSCALED) + gx = x·Mx + cv --------------
    unsigned short* As = (unsigned short*)SMEM;   // [kb][m][8], 32 KB
    int mb = blockIdx.x - nP2;
    bool us = mb < NBU;
    int tile = us ? mb : mb - NBU;
    const float* x = us ? xU : xI;
    const unsigned short* Wsw = us ? WswU : WswI;
    unsigned short* y = us ? yU : yI;
    const float* Mx = mats + (us ? 0 : 512);
    const float* cv = mats + (us ? 1024 : 1026);
    float2* gx = us ? gxU : gxI;
    int n = us ? NU : NI;
    int row0 = tile << 7;

    for (int it = 0; it < 16; ++it) {
        int i = it * 256 + t;
        int m = i >> 5, c4 = i & 31;
        int row = row0 + m;
        float4 v = (row < n) ? ((const float4*)x)[(size_t)row * 32 + c4]
                             : make_float4(0.f, 0.f, 0.f, 0.f);
        int k0 = c4 * 4;
        ushort4 s4; s4.x = f2bf(v.x); s4.y = f2bf(v.y); s4.z = f2bf(v.z); s4.w = f2bf(v.w);
        *(ushort4*)&As[((k0 >> 3) * 128 + m) * 8 + (k0 & 7)] = s4;
    }
    __syncthreads();

    int w = t >> 6, l = t & 63;
    int lane15 = l & 15, quad = l >> 4;

    f32x4 acc[2][8];
    #pragma unroll
    for (int rt = 0; rt < 2; ++rt)
        #pragma unroll
        for (int c = 0; c < 8; ++c) acc[rt][c] = (f32x4){0.f, 0.f, 0.f, 0.f};

    #pragma unroll
    for (int ks = 0; ks < 4; ++ks) {
        int kb = ks * 4 + quad;
        bf16x8 a0 = *(const bf16x8*)&As[(kb * 128 + w * 32 + lane15) * 8];
        bf16x8 a1 = *(const bf16x8*)&As[(kb * 128 + w * 32 + 16 + lane15) * 8];
        #pragma unroll
        for (int c = 0; c < 8; ++c) {
            bf16x8 b = *(const bf16x8*)&Wsw[(size_t)(kb * 128 + c * 16 + lane15) * 8];
            acc[0][c] = __builtin_amdgcn_mfma_f32_16x16x32_bf16(a0, b, acc[0][c], 0, 0, 0);
            acc[1][c] = __builtin_amdgcn_mfma_f32_16x16x32_bf16(a1, b, acc[1][c], 0, 0, 0);
        }
    }

    {   // gx from As (bf16 x): 2 threads per row
        int row = t >> 1, cc = t & 1;
        float p = 0.f;
        for (int kb = 0; kb < 16; ++kb) {
            const unsigned short* ap = &As[(kb * 128 + row) * 8];
            #pragma unroll
            for (int j = 0; j < 8; ++j)
                p += bfu(ap[j]) * Mx[(kb * 8 + j) * 2 + cc];
        }
        int grow = row0 + row;
        if (grow < n) ((float*)&gx[grow])[cc] = p + cv[cc];
    }
    __syncthreads();                       // all As reads done; reuse for transpose

    const int LSTR = 136;                  // 128x136 ushorts = 34816 B exactly
    unsigned short* SMu = (unsigned short*)SMEM;
    unsigned short* Lw = SMu + w * 32 * LSTR;
    #pragma unroll
    for (int rt = 0; rt < 2; ++rt) {
        #pragma unroll
        for (int r = 0; r < 4; ++r) {
            int lrow = rt * 16 + quad * 4 + r;
            #pragma unroll
            for (int c = 0; c < 8; ++c)
                Lw[lrow * LSTR + c * 16 + lane15] = f2bf(acc[rt][c][r]);
        }
    }
    #pragma unroll
    for (int pass = 0; pass < 8; ++pass) {
        int lrow = pass * 4 + quad;
        int grow = row0 + w * 32 + lrow;
        uint4 v = *(uint4*)&Lw[lrow * LSTR + lane15 * 8];
        if (grow < n) *(uint4*)&y[(size_t)grow * 128 + lane15 * 8] = v;
    }
}

// ==== K3: gather (both sides), 16 lanes/node, per-neighbor invo fma ======
__global__ __launch_bounds__(256) void gather_kernel(
    const int2* __restrict__ offU, const int* __restrict__ valU,
    const int2* __restrict__ offI, const int* __restrict__ valI,
    const unsigned short* __restrict__ yU, const unsigned short* __restrict__ yI,
    const float* __restrict__ invU, const float* __restrict__ invI,
    const float* __restrict__ b0, const float* __restrict__ b1,
    const float* __restrict__ mats,
    const float2* __restrict__ gxU, const float2* __restrict__ gxI,
    float2* __restrict__ su, float2* __restrict__ si,
    int NU, int NI, int GU) {
    bool us = blockIdx.x < (unsigned)GU;
    int nb = us ? blockIdx.x : blockIdx.x - GU;
    const int2* off = us ? offU : offI;
    const int* val = us ? valU : valI;
    const unsigned short* yo = us ? yI : yU;
    const float* invo = us ? invI : invU;     // neighbor-side inv (deferred scale)
    const float* inv = us ? invU : invI;
    const float* bv = us ? b1 : b0;
    const float* Mh = mats + (us ? 256 : 768);
    const float2* gx = us ? gxU : gxI;
    float2* so = us ? su : si;
    int n = us ? NU : NI;

    int g = threadIdx.x >> 4, t = threadIdx.x & 15, j0 = t * 8;
    int u = nb * 16 + g;
    if (u >= n) return;

    float a0 = 0, a1 = 0, a2 = 0, a3 = 0, a4 = 0, a5 = 0, a6 = 0, a7 = 0;
    int2 oe = off[u];
    int k = oe.x, end = oe.y;
    for (; k + 4 <= end; k += 4) {
        int v0 = val[k], v1 = val[k + 1], v2 = val[k + 2], v3 = val[k + 3];
        float i0 = invo[v0], i1 = invo[v1], i2 = invo[v2], i3 = invo[v3];
        uint4 w0 = *(const uint4*)(yo + (size_t)v0 * H + j0);
        uint4 w1 = *(const uint4*)(yo + (size_t)v1 * H + j0);
        uint4 w2 = *(const uint4*)(yo + (size_t)v2 * H + j0);
        uint4 w3 = *(const uint4*)(yo + (size_t)v3 * H + j0);
        a0 += bflo(w0.x) * i0 + bflo(w1.x) * i1 + bflo(w2.x) * i2 + bflo(w3.x) * i3;
        a1 += bfhi(w0.x) * i0 + bfhi(w1.x) * i1 + bfhi(w2.x) * i2 + bfhi(w3.x) * i3;
        a2 += bflo(w0.y) * i0 + bflo(w1.y) * i1 + bflo(w2.y) * i2 + bflo(w3.y) * i3;
        a3 += bfhi(w0.y) * i0 + bfhi(w1.y) * i1 + bfhi(w2.y) * i2 + bfhi(w3.y) * i3;
        a4 += bflo(w0.z) * i0 + bflo(w1.z) * i1 + bflo(w2.z) * i2 + bflo(w3.z) * i3;
        a5 += bfhi(w0.z) * i0 + bfhi(w1.z) * i1 + bfhi(w2.z) * i2 + bfhi(w3.z) * i3;
        a6 += bflo(w0.w) * i0 + bflo(w1.w) * i1 + bflo(w2.w) * i2 + bflo(w3.w) * i3;
        a7 += bfhi(w0.w) * i0 + bfhi(w1.w) * i1 + bfhi(w2.w) * i2 + bfhi(w3.w) * i3;
    }
    for (; k < end; ++k) {
        int v0 = val[k];
        float i0 = invo[v0];
        uint4 w0 = *(const uint4*)(yo + (size_t)v0 * H + j0);
        a0 += bflo(w0.x) * i0; a1 += bfhi(w0.x) * i0;
        a2 += bflo(w0.y) * i0; a3 += bfhi(w0.y) * i0;
        a4 += bflo(w0.z) * i0; a5 += bfhi(w0.z) * i0;
        a6 += bflo(w0.w) * i0; a7 += bfhi(w0.w) * i0;
    }
    float iv = inv[u];
    float4 bb0 = *(const float4*)(bv + j0), bb1 = *(const float4*)(bv + j0 + 4);
    float h0 = fmaxf(a0 * iv + bb0.x, 0.f), h1 = fmaxf(a1 * iv + bb0.y, 0.f);
    float h2 = fmaxf(a2 * iv + bb0.z, 0.f), h3 = fmaxf(a3 * iv + bb0.w, 0.f);
    float h4 = fmaxf(a4 * iv + bb1.x, 0.f), h5 = fmaxf(a5 * iv + bb1.y, 0.f);
    float h6 = fmaxf(a6 * iv + bb1.z, 0.f), h7 = fmaxf(a7 * iv + bb1.w, 0.f);
    float4 m0 = *(const float4*)(Mh + j0 * 2),      m1 = *(const float4*)(Mh + j0 * 2 + 4);
    float4 m2 = *(const float4*)(Mh + j0 * 2 + 8),  m3 = *(const float4*)(Mh + j0 * 2 + 12);
    float p0 = h0 * m0.x + h1 * m0.z + h2 * m1.x + h3 * m1.z
             + h4 * m2.x + h5 * m2.z + h6 * m3.x + h7 * m3.z;
    float p1 = h0 * m0.y + h1 * m0.w + h2 * m1.y + h3 * m1.w
             + h4 * m2.y + h5 * m2.w + h6 * m3.y + h7 * m3.w;
    #pragma unroll
    for (int o = 1; o < 16; o <<= 1) { p0 += __shfl_xor(p0, o); p1 += __shfl_xor(p1, o); }
    if (t == 0) {
        float2 gg = gx[u];
        so[u] = make_float2(p0 + gg.x, p1 + gg.y);
    }
}

__global__ void edge_kernel(const int* __restrict__ src, const int* __restrict__ dst,
                            const float2* __restrict__ su, const float2* __restrict__ si,
                            float2* __restrict__ out, int E) {
    int e0 = (blockIdx.x * 256 + threadIdx.x) * 2;
    if (e0 >= E) return;
    int2 s2 = *(const int2*)(src + e0);
    int2 d2 = *(const int2*)(dst + e0);
    float2 a = su[s2.x], b = si[d2.x];
    float l0 = a.x + b.x, l1 = a.y + b.y;
    float m = fmaxf(l0, l1);
    float q0 = __expf(l0 - m), q1 = __expf(l1 - m);
    float r = 1.0f / (q0 + q1);
    out[e0] = make_float2(q0 * r, q1 * r);
    if (e0 + 1 < E) {
        a = su[s2.y]; b = si[d2.y];
        l0 = a.x + b.x; l1 = a.y + b.y;
        m = fmaxf(l0, l1);
        q0 = __expf(l0 - m); q1 = __expf(l1 - m);
        r = 1.0f / (q0 + q1);
        out[e0 + 1] = make_float2(q0 * r, q1 * r);
    }
}

extern "C" void kernel_launch(void* const* d_in, const int* in_sizes, int n_in,
                              void* d_out, int out_size, void* d_ws, size_t ws_size,
                              hipStream_t stream) {
    const float* x_user = (const float*)d_in[0];
    const float* x_item = (const float*)d_in[1];
    const float* W0 = (const float*)d_in[2];
    const float* b0 = (const float*)d_in[3];
    const float* W1 = (const float*)d_in[4];
    const float* b1 = (const float*)d_in[5];
    const float* W2 = (const float*)d_in[6];
    const float* b2 = (const float*)d_in[7];
    const float* W3 = (const float*)d_in[8];
    const float* b3 = (const float*)d_in[9];
    const float* Wp = (const float*)d_in[10];
    const float* bp = (const float*)d_in[11];
    const int* esrc = (const int*)d_in[12];
    const int* edst = (const int*)d_in[13];

    const int NU = in_sizes[0] / H;
    const int NI = in_sizes[1] / H;
    const int E  = in_sizes[12];
    const int NBU = (NU + 127) >> 7;
    const int NBI = (NI + 127) >> 7;
    const int GU = (NU + 15) >> 4, GI = (NI + 15) >> 4;
    auto topshift = [](int n) {
        int bits = 32 - __builtin_clz((unsigned)(n - 1));
        return bits > 3 ? bits - 3 : 0;
    };
    const int shiftU = topshift(NI);
    const int shiftI = topshift(NU);

    auto rnd = [](size_t x) { return (x + 63) & ~(size_t)63; };
    char* base = (char*)d_ws;
    size_t o = 0;
    auto alloc = [&](size_t elems) { void* p = base + o * 4; o += rnd(elems); return p; };

    float* inv_du = (float*)alloc(NU);
    float* inv_di = (float*)alloc(NI);
    float2* su    = (float2*)alloc((size_t)NU * 2);
    float2* si    = (float2*)alloc((size_t)NI * 2);
    float2* gxU   = (float2*)alloc((size_t)NU * 2);
    float2* gxI   = (float2*)alloc((size_t)NI * 2);
    float* mats   = (float*)alloc(1056);
    size_t cur_off = o;
    int* gCurU = (int*)alloc(NBU);
    int* gCurI = (int*)alloc(NBI);
    size_t cur_words = o - cur_off;
    int2* offU = (int2*)alloc((size_t)NU * 2);
    int2* offI = (int2*)alloc((size_t)NI * 2);
    int* valU  = (int*)alloc((size_t)NBU * CAPU);
    int* valI  = (int*)alloc((size_t)NBI * CAPI);
    unsigned* pairU = (unsigned*)alloc((size_t)NBU * CAPU);
    unsigned* pairI = (unsigned*)alloc((size_t)NBI * CAPI);
    unsigned short* WswU = (unsigned short*)alloc(8192);
    unsigned short* WswI = (unsigned short*)alloc(8192);
    unsigned short* yU = (unsigned short*)alloc((size_t)NU * 64);
    unsigned short* yI = (unsigned short*)alloc((size_t)NI * 64);

    hipMemsetAsync(gCurU, 0, cur_words * 4, stream);

    int p1_blocks = (E + 2047) / 2048;
    k1_prep_p1<<<3 + p1_blocks, 256, 0, stream>>>(
        W0, W1, W2, b2, W3, b3, Wp, bp, mats, WswU, WswI,
        esrc, edst, gCurU, gCurI, pairU, pairI, E, NBU, NBI);

    k2_build_mfma<<<2 * (NBU + NBI), 256, 0, stream>>>(
        pairU, pairI, gCurU, gCurI, offU, offI, inv_du, inv_di, valU, valI,
        x_user, x_item, WswU, WswI, yU, yI, mats, gxU, gxI,
        NU, NI, NBU, NBI, shiftU, shiftI);

    gather_kernel<<<GU + GI, 256, 0, stream>>>(
        offU, valU, offI, valI, yU, yI, inv_du, inv_di, b0, b1, mats,
        gxU, gxI, su, si, NU, NI, GU);

    edge_kernel<<<(E / 2 + 255) / 256, 256, 0, stream>>>(esrc, edst, su, si, (float2*)d_out, E);
}

// Round 7
// 283.273 us; speedup vs baseline: 13.1713x; 1.0701x over previous
//
#include <hip/hip_runtime.h>
#include <hip/hip_bf16.h>

// GraphConv x2 + per-type linear + edge MLP + softmax(2).
// R7: 2-pass radix CSR build. Pass A: 196 coarse buckets/side (longer write
//     runs, kills partial-line amplification that made p1 ~120us). Pass B:
//     one block per coarse bucket, LDS counting sort, fully coalesced val
//     write. K2 = 392 passB blocks + 1173 mfma blocks (real overlap now).

#define H 128
#define CAPC 6656          // coarse-bucket capacity (mean ~5.1K, +20 sigma)

typedef __attribute__((ext_vector_type(8))) short bf16x8;
typedef __attribute__((ext_vector_type(4))) float f32x4;

__device__ __forceinline__ unsigned short f2bf(float f) {
    unsigned u = __float_as_uint(f);
    unsigned r = (u + 0x7fffu + ((u >> 16) & 1u)) >> 16;   // RNE
    return (unsigned short)r;
}
__device__ __forceinline__ float bflo(unsigned b) { return __uint_as_float(b << 16); }
__device__ __forceinline__ float bfhi(unsigned b) { return __uint_as_float(b & 0xffff0000u); }
__device__ __forceinline__ float bfu(unsigned short b) { return __uint_as_float((unsigned)b << 16); }

// ==== K1: block0 = fold; blocks1-2 = W swizzle; blocks3+ = pass A ========
// mats layout: Ax[256] | Ah[256] | Bx[256] | Bh[256] | cu[2] | ci[2]
__global__ __launch_bounds__(256) void k1_prep_pA(
    const float* __restrict__ W0, const float* __restrict__ W1,
    const float* __restrict__ W2, const float* __restrict__ b2,
    const float* __restrict__ W3, const float* __restrict__ b3,
    const float* __restrict__ Wp, const float* __restrict__ bp,
    float* __restrict__ mats,
    unsigned short* __restrict__ WswU, unsigned short* __restrict__ WswI,
    const int* __restrict__ src, const int* __restrict__ dst,
    int* __restrict__ gCurU, int* __restrict__ gCurI,
    unsigned* __restrict__ pairU, unsigned* __restrict__ pairI,
    int E, int ncu, int nci) {
    __shared__ int cntU[256], baseU[256], cntI[256], baseI[256];
    int bx = blockIdx.x, t = threadIdx.x;
    if (bx == 0) {
        int j = t >> 1, c = t & 1;
        float ax = 0.f, ah = 0.f, bx2 = 0.f, bh = 0.f;
        for (int m = 0; m < H; ++m) {
            float wpu = Wp[m * 2 + c];
            float wpi = Wp[(H + m) * 2 + c];
            ax += W2[j * H + m] * wpu;
            ah += W2[(H + j) * H + m] * wpu;
            bx2 += W3[j * H + m] * wpi;
            bh += W3[(H + j) * H + m] * wpi;
        }
        mats[      j * 2 + c] = ax;
        mats[256 + j * 2 + c] = ah;
        mats[512 + j * 2 + c] = bx2;
        mats[768 + j * 2 + c] = bh;
        if (t < 2) {
            float s1 = 0.f, s2 = 0.f;
            for (int m = 0; m < H; ++m) {
                s1 += b2[m] * Wp[m * 2 + t];
                s2 += b3[m] * Wp[(H + m) * 2 + t];
            }
            mats[1024 + t] = s1 + bp[t];
            mats[1026 + t] = s2;
        }
        return;
    }
    if (bx <= 2) {
        const float* W = (bx == 1) ? W0 : W1;
        unsigned short* o = (bx == 1) ? WswU : WswI;
        for (int i = t; i < 4096; i += 256) {
            float4 w = ((const float4*)W)[i];
            int k = i >> 5, n0 = (i & 31) * 4;
            int kb = k >> 3, kj = k & 7;
            o[(kb * 128 + n0 + 0) * 8 + kj] = f2bf(w.x);
            o[(kb * 128 + n0 + 1) * 8 + kj] = f2bf(w.y);
            o[(kb * 128 + n0 + 2) * 8 + kj] = f2bf(w.z);
            o[(kb * 128 + n0 + 3) * 8 + kj] = f2bf(w.w);
        }
        return;
    }
    // ---- pass A: coarse partition (user key = s>>9, item key = d>>8) ----
    int t0 = (bx - 3) * 4096;
    cntU[t] = 0; cntI[t] = 0;
    __syncthreads();
    #pragma unroll
    for (int j = 0; j < 16; ++j) {
        int e = t0 + j * 256 + t;
        if (e < E) { atomicAdd(&cntU[src[e] >> 9], 1); atomicAdd(&cntI[dst[e] >> 8], 1); }
    }
    __syncthreads();
    if (t < ncu) { int c = cntU[t]; baseU[t] = c ? (CAPC * t + atomicAdd(&gCurU[t], c)) : 0; }
    if (t < nci) { int c = cntI[t]; baseI[t] = c ? (CAPC * t + atomicAdd(&gCurI[t], c)) : 0; }
    __syncthreads();
    #pragma unroll
    for (int j = 0; j < 16; ++j) {
        int e = t0 + j * 256 + t;
        if (e < E) {
            int s = src[e], d = dst[e];
            int bu = s >> 9, bi = d >> 8;
            int r1 = atomicSub(&cntU[bu], 1) - 1;
            int i1 = baseU[bu] + r1;
            if (i1 < CAPC * (bu + 1))
                pairU[i1] = ((unsigned)(s & 511) << 20) | (unsigned)d;
            int r2 = atomicSub(&cntI[bi], 1) - 1;
            int i2 = baseI[bi] + r2;
            if (i2 < CAPC * (bi + 1))
                pairI[i2] = ((unsigned)(d & 255) << 20) | (unsigned)s;
        }
    }
}

// ==== K2: blocks [0, ncu+nci) = pass B CSR build; rest = mfma y/gx =======
__global__ __launch_bounds__(256) void k2_build_mfma(
    const unsigned* __restrict__ pairU, const unsigned* __restrict__ pairI,
    const int* __restrict__ gCurU, const int* __restrict__ gCurI,
    int2* __restrict__ offU, int2* __restrict__ offI,
    float* __restrict__ invU, float* __restrict__ invI,
    int* __restrict__ valU, int* __restrict__ valI,
    const float* __restrict__ xU, const float* __restrict__ xI,
    const unsigned short* __restrict__ WswU, const unsigned short* __restrict__ WswI,
    unsigned short* __restrict__ yU, unsigned short* __restrict__ yI,
    const float* __restrict__ mats,
    float2* __restrict__ gxU, float2* __restrict__ gxI,
    int NU, int NI, int ncu, int nci, int NBU, int NBI) {
    __shared__ __align__(16) char SMEM[34816];
    int nPB = ncu + nci;
    int t = threadIdx.x;

    if (blockIdx.x < (unsigned)nPB) {
        // ---- pass B: per-coarse-bucket counting sort by local node ------
        bool us = blockIdx.x < (unsigned)ncu;
        int cb = us ? blockIdx.x : blockIdx.x - ncu;
        const unsigned* pairs = us ? pairU : pairI;
        int size = us ? gCurU[cb] : gCurI[cb];
        if (size > CAPC) size = CAPC;
        int start = cb * CAPC;
        int nodesPer = us ? 512 : 256;
        int nodeBase = cb * nodesPer;
        int n = us ? NU : NI;
        int2* off = us ? offU : offI;
        float* inv = us ? invU : invI;
        int* val = us ? valU : valI;

        int* cnt  = (int*)SMEM;            // nodesPer
        int* pref = cnt + nodesPer;        // nodesPer
        int* part = pref + nodesPer;       // 256
        int* stage = part + 256;           // CAPC

        for (int i = t; i < nodesPer; i += 256) cnt[i] = 0;
        __syncthreads();
        for (int i = t; i < size; i += 256) atomicAdd(&cnt[pairs[start + i] >> 20], 1);
        __syncthreads();
        int g = nodesPer >> 8;             // 2 (users) or 1 (items)
        int b0 = t * g;
        int lv0 = cnt[b0], lv1 = (g == 2) ? cnt[b0 + 1] : 0;
        int lsum = lv0 + lv1;
        part[t] = lsum; __syncthreads();
        for (int o2 = 1; o2 < 256; o2 <<= 1) {
            int v = (t >= o2) ? part[t - o2] : 0; __syncthreads();
            part[t] += v; __syncthreads();
        }
        int excl = part[t] - lsum;
        pref[b0] = excl;
        if (g == 2) pref[b0 + 1] = excl + lv0;
        __syncthreads();
        for (int i = t; i < nodesPer; i += 256) {
            int node = nodeBase + i;
            if (node < n) {
                int st = pref[i];
                off[node] = make_int2(start + st, start + st + cnt[i]);
                inv[node] = rsqrtf(fmaxf((float)cnt[i], 1.0f));
            }
        }
        __syncthreads();
        for (int i = t; i < size; i += 256) {
            unsigned p = pairs[start + i];
            int r = atomicAdd(&pref[p >> 20], 1);
            stage[r] = (int)(p & 0xFFFFFu);
        }
        __syncthreads();
        for (int i = t; i < size; i += 256) val[start + i] = stage[i];
        return;
    }

    // ---- mfma: y = x @ W (bf16, unscaled) + gx = x·Mx + cv --------------
    unsigned short* As = (unsigned short*)SMEM;   // [kb][m][8], 32 KB
    int mb = blockIdx.x - nPB;
    bool us = mb < NBU;
    int tile = us ? mb : mb - NBU;
    const float* x = us ? xU : xI;
    const unsigned short* Wsw = us ? WswU : WswI;
    unsigned short* y = us ? yU : yI;
    const float* Mx = mats + (us ? 0 : 512);
    const float* cv = mats + (us ? 1024 : 1026);
    float2* gx = us ? gxU : gxI;
    int n = us ? NU : NI;
    int row0 = tile << 7;

    for (int it = 0; it < 16; ++it) {
        int i = it * 256 + t;
        int m = i >> 5, c4 = i & 31;
        int row = row0 + m;
        float4 v = (row < n) ? ((const float4*)x)[(size_t)row * 32 + c4]
                             : make_float4(0.f, 0.f, 0.f, 0.f);
        int k0 = c4 * 4;
        ushort4 s4; s4.x = f2bf(v.x); s4.y = f2bf(v.y); s4.z = f2bf(v.z); s4.w = f2bf(v.w);
        *(ushort4*)&As[((k0 >> 3) * 128 + m) * 8 + (k0 & 7)] = s4;
    }
    __syncthreads();

    int w = t >> 6, l = t & 63;
    int lane15 = l & 15, quad = l >> 4;

    f32x4 acc[2][8];
    #pragma unroll
    for (int rt = 0; rt < 2; ++rt)
        #pragma unroll
        for (int c = 0; c < 8; ++c) acc[rt][c] = (f32x4){0.f, 0.f, 0.f, 0.f};

    #pragma unroll
    for (int ks = 0; ks < 4; ++ks) {
        int kb = ks * 4 + quad;
        bf16x8 a0 = *(const bf16x8*)&As[(kb * 128 + w * 32 + lane15) * 8];
        bf16x8 a1 = *(const bf16x8*)&As[(kb * 128 + w * 32 + 16 + lane15) * 8];
        #pragma unroll
        for (int c = 0; c < 8; ++c) {
            bf16x8 b = *(const bf16x8*)&Wsw[(size_t)(kb * 128 + c * 16 + lane15) * 8];
            acc[0][c] = __builtin_amdgcn_mfma_f32_16x16x32_bf16(a0, b, acc[0][c], 0, 0, 0);
            acc[1][c] = __builtin_amdgcn_mfma_f32_16x16x32_bf16(a1, b, acc[1][c], 0, 0, 0);
        }
    }

    {   // gx from As (bf16 x): 2 threads per row
        int row = t >> 1, cc = t & 1;
        float p = 0.f;
        for (int kb = 0; kb < 16; ++kb) {
            const unsigned short* ap = &As[(kb * 128 + row) * 8];
            #pragma unroll
            for (int j = 0; j < 8; ++j)
                p += bfu(ap[j]) * Mx[(kb * 8 + j) * 2 + cc];
        }
        int grow = row0 + row;
        if (grow < n) ((float*)&gx[grow])[cc] = p + cv[cc];
    }
    __syncthreads();                       // all As reads done; reuse LDS

    const int LSTR = 136;                  // 128x136 ushorts = 34816 B exactly
    unsigned short* SMu = (unsigned short*)SMEM;
    unsigned short* Lw = SMu + w * 32 * LSTR;
    #pragma unroll
    for (int rt = 0; rt < 2; ++rt) {
        #pragma unroll
        for (int r = 0; r < 4; ++r) {
            int lrow = rt * 16 + quad * 4 + r;
            #pragma unroll
            for (int c = 0; c < 8; ++c)
                Lw[lrow * LSTR + c * 16 + lane15] = f2bf(acc[rt][c][r]);
        }
    }
    #pragma unroll
    for (int pass = 0; pass < 8; ++pass) {
        int lrow = pass * 4 + quad;
        int grow = row0 + w * 32 + lrow;
        uint4 v = *(uint4*)&Lw[lrow * LSTR + lane15 * 8];
        if (grow < n) *(uint4*)&y[(size_t)grow * 128 + lane15 * 8] = v;
    }
}

// ==== K3: gather (both sides), 16 lanes/node, per-neighbor invo fma ======
__global__ __launch_bounds__(256) void gather_kernel(
    const int2* __restrict__ offU, const int* __restrict__ valU,
    const int2* __restrict__ offI, const int* __restrict__ valI,
    const unsigned short* __restrict__ yU, const unsigned short* __restrict__ yI,
    const float* __restrict__ invU, const float* __restrict__ invI,
    const float* __restrict__ b0, const float* __restrict__ b1,
    const float* __restrict__ mats,
    const float2* __restrict__ gxU, const float2* __restrict__ gxI,
    float2* __restrict__ su, float2* __restrict__ si,
    int NU, int NI, int GU) {
    bool us = blockIdx.x < (unsigned)GU;
    int nb = us ? blockIdx.x : blockIdx.x - GU;
    const int2* off = us ? offU : offI;
    const int* val = us ? valU : valI;
    const unsigned short* yo = us ? yI : yU;
    const float* invo = us ? invI : invU;     // neighbor-side inv (deferred)
    const float* inv = us ? invU : invI;
    const float* bv = us ? b1 : b0;
    const float* Mh = mats + (us ? 256 : 768);
    const float2* gx = us ? gxU : gxI;
    float2* so = us ? su : si;
    int n = us ? NU : NI;

    int g = threadIdx.x >> 4, t = threadIdx.x & 15, j0 = t * 8;
    int u = nb * 16 + g;
    if (u >= n) return;

    float a0 = 0, a1 = 0, a2 = 0, a3 = 0, a4 = 0, a5 = 0, a6 = 0, a7 = 0;
    int2 oe = off[u];
    int k = oe.x, end = oe.y;
    for (; k + 4 <= end; k += 4) {
        int v0 = val[k], v1 = val[k + 1], v2 = val[k + 2], v3 = val[k + 3];
        float i0 = invo[v0], i1 = invo[v1], i2 = invo[v2], i3 = invo[v3];
        uint4 w0 = *(const uint4*)(yo + (size_t)v0 * H + j0);
        uint4 w1 = *(const uint4*)(yo + (size_t)v1 * H + j0);
        uint4 w2 = *(const uint4*)(yo + (size_t)v2 * H + j0);
        uint4 w3 = *(const uint4*)(yo + (size_t)v3 * H + j0);
        a0 += bflo(w0.x) * i0 + bflo(w1.x) * i1 + bflo(w2.x) * i2 + bflo(w3.x) * i3;
        a1 += bfhi(w0.x) * i0 + bfhi(w1.x) * i1 + bfhi(w2.x) * i2 + bfhi(w3.x) * i3;
        a2 += bflo(w0.y) * i0 + bflo(w1.y) * i1 + bflo(w2.y) * i2 + bflo(w3.y) * i3;
        a3 += bfhi(w0.y) * i0 + bfhi(w1.y) * i1 + bfhi(w2.y) * i2 + bfhi(w3.y) * i3;
        a4 += bflo(w0.z) * i0 + bflo(w1.z) * i1 + bflo(w2.z) * i2 + bflo(w3.z) * i3;
        a5 += bfhi(w0.z) * i0 + bfhi(w1.z) * i1 + bfhi(w2.z) * i2 + bfhi(w3.z) * i3;
        a6 += bflo(w0.w) * i0 + bflo(w1.w) * i1 + bflo(w2.w) * i2 + bflo(w3.w) * i3;
        a7 += bfhi(w0.w) * i0 + bfhi(w1.w) * i1 + bfhi(w2.w) * i2 + bfhi(w3.w) * i3;
    }
    for (; k < end; ++k) {
        int v0 = val[k];
        float i0 = invo[v0];
        uint4 w0 = *(const uint4*)(yo + (size_t)v0 * H + j0);
        a0 += bflo(w0.x) * i0; a1 += bfhi(w0.x) * i0;
        a2 += bflo(w0.y) * i0; a3 += bfhi(w0.y) * i0;
        a4 += bflo(w0.z) * i0; a5 += bfhi(w0.z) * i0;
        a6 += bflo(w0.w) * i0; a7 += bfhi(w0.w) * i0;
    }
    float iv = inv[u];
    float4 bb0 = *(const float4*)(bv + j0), bb1 = *(const float4*)(bv + j0 + 4);
    float h0 = fmaxf(a0 * iv + bb0.x, 0.f), h1 = fmaxf(a1 * iv + bb0.y, 0.f);
    float h2 = fmaxf(a2 * iv + bb0.z, 0.f), h3 = fmaxf(a3 * iv + bb0.w, 0.f);
    float h4 = fmaxf(a4 * iv + bb1.x, 0.f), h5 = fmaxf(a5 * iv + bb1.y, 0.f);
    float h6 = fmaxf(a6 * iv + bb1.z, 0.f), h7 = fmaxf(a7 * iv + bb1.w, 0.f);
    float4 m0 = *(const float4*)(Mh + j0 * 2),      m1 = *(const float4*)(Mh + j0 * 2 + 4);
    float4 m2 = *(const float4*)(Mh + j0 * 2 + 8),  m3 = *(const float4*)(Mh + j0 * 2 + 12);
    float p0 = h0 * m0.x + h1 * m0.z + h2 * m1.x + h3 * m1.z
             + h4 * m2.x + h5 * m2.z + h6 * m3.x + h7 * m3.z;
    float p1 = h0 * m0.y + h1 * m0.w + h2 * m1.y + h3 * m1.w
             + h4 * m2.y + h5 * m2.w + h6 * m3.y + h7 * m3.w;
    #pragma unroll
    for (int o = 1; o < 16; o <<= 1) { p0 += __shfl_xor(p0, o); p1 += __shfl_xor(p1, o); }
    if (t == 0) {
        float2 gg = gx[u];
        so[u] = make_float2(p0 + gg.x, p1 + gg.y);
    }
}

__global__ void edge_kernel(const int* __restrict__ src, const int* __restrict__ dst,
                            const float2* __restrict__ su, const float2* __restrict__ si,
                            float2* __restrict__ out, int E) {
    int e0 = (blockIdx.x * 256 + threadIdx.x) * 2;
    if (e0 >= E) return;
    int2 s2 = *(const int2*)(src + e0);
    int2 d2 = *(const int2*)(dst + e0);
    float2 a = su[s2.x], b = si[d2.x];
    float l0 = a.x + b.x, l1 = a.y + b.y;
    float m = fmaxf(l0, l1);
    float q0 = __expf(l0 - m), q1 = __expf(l1 - m);
    float r = 1.0f / (q0 + q1);
    out[e0] = make_float2(q0 * r, q1 * r);
    if (e0 + 1 < E) {
        a = su[s2.y]; b = si[d2.y];
        l0 = a.x + b.x; l1 = a.y + b.y;
        m = fmaxf(l0, l1);
        q0 = __expf(l0 - m); q1 = __expf(l1 - m);
        r = 1.0f / (q0 + q1);
        out[e0 + 1] = make_float2(q0 * r, q1 * r);
    }
}

extern "C" void kernel_launch(void* const* d_in, const int* in_sizes, int n_in,
                              void* d_out, int out_size, void* d_ws, size_t ws_size,
                              hipStream_t stream) {
    const float* x_user = (const float*)d_in[0];
    const float* x_item = (const float*)d_in[1];
    const float* W0 = (const float*)d_in[2];
    const float* b0 = (const float*)d_in[3];
    const float* W1 = (const float*)d_in[4];
    const float* b1 = (const float*)d_in[5];
    const float* W2 = (const float*)d_in[6];
    const float* b2 = (const float*)d_in[7];
    const float* W3 = (const float*)d_in[8];
    const float* b3 = (const float*)d_in[9];
    const float* Wp = (const float*)d_in[10];
    const float* bp = (const float*)d_in[11];
    const int* esrc = (const int*)d_in[12];
    const int* edst = (const int*)d_in[13];

    const int NU = in_sizes[0] / H;
    const int NI = in_sizes[1] / H;
    const int E  = in_sizes[12];
    const int NCU = (NU + 511) >> 9;          // coarse buckets (512 nodes)
    const int NCI = (NI + 255) >> 8;          // coarse buckets (256 nodes)
    const int NBU = (NU + 127) >> 7;          // mfma tiles
    const int NBI = (NI + 127) >> 7;
    const int GU = (NU + 15) >> 4, GI = (NI + 15) >> 4;

    auto rnd = [](size_t x) { return (x + 63) & ~(size_t)63; };
    char* base = (char*)d_ws;
    size_t o = 0;
    auto alloc = [&](size_t elems) { void* p = base + o * 4; o += rnd(elems); return p; };

    float* inv_du = (float*)alloc(NU);
    float* inv_di = (float*)alloc(NI);
    float2* su    = (float2*)alloc((size_t)NU * 2);
    float2* si    = (float2*)alloc((size_t)NI * 2);
    float2* gxU   = (float2*)alloc((size_t)NU * 2);
    float2* gxI   = (float2*)alloc((size_t)NI * 2);
    float* mats   = (float*)alloc(1056);
    size_t cur_off = o;
    int* gCurU = (int*)alloc(NCU);
    int* gCurI = (int*)alloc(NCI);
    size_t cur_words = o - cur_off;
    int2* offU = (int2*)alloc((size_t)NU * 2);
    int2* offI = (int2*)alloc((size_t)NI * 2);
    int* valU  = (int*)alloc((size_t)NCU * CAPC);
    int* valI  = (int*)alloc((size_t)NCI * CAPC);
    unsigned* pairU = (unsigned*)alloc((size_t)NCU * CAPC);
    unsigned* pairI = (unsigned*)alloc((size_t)NCI * CAPC);
    unsigned short* WswU = (unsigned short*)alloc(8192);
    unsigned short* WswI = (unsigned short*)alloc(8192);
    unsigned short* yU = (unsigned short*)alloc((size_t)NU * 64);
    unsigned short* yI = (unsigned short*)alloc((size_t)NI * 64);

    hipMemsetAsync(gCurU, 0, cur_words * 4, stream);

    int pa_blocks = (E + 4095) / 4096;
    k1_prep_pA<<<3 + pa_blocks, 256, 0, stream>>>(
        W0, W1, W2, b2, W3, b3, Wp, bp, mats, WswU, WswI,
        esrc, edst, gCurU, gCurI, pairU, pairI, E, NCU, NCI);

    k2_build_mfma<<<NCU + NCI + NBU + NBI, 256, 0, stream>>>(
        pairU, pairI, gCurU, gCurI, offU, offI, inv_du, inv_di, valU, valI,
        x_user, x_item, WswU, WswI, yU, yI, mats, gxU, gxI,
        NU, NI, NCU, NCI, NBU, NBI);

    gather_kernel<<<GU + GI, 256, 0, stream>>>(
        offU, valU, offI, valI, yU, yI, inv_du, inv_di, b0, b1, mats,
        gxU, gxI, su, si, NU, NI, GU);

    edge_kernel<<<(E / 2 + 255) / 256, 256, 0, stream>>>(esrc, edst, su, si, (float2*)d_out, E);
}